// Round 1
// baseline (302.643 us; speedup 1.0000x reference)
//
#include <hip/hip_runtime.h>

#define BB 4
#define SS 4096
#define DD 1024
#define HH 16
#define DVV 64

// ---------------------------------------------------------------------------
// K1: qh = sigmoid(q@wq+bq), kh = sigmoid(k@wk+bk)   (B,S,H) each
// block = 512 threads (8 waves): waves 0-3 -> k matrix, 4-7 -> q matrix,
// each wave owns 4 heads; weights live in 64 VGPRs per lane.
// ---------------------------------------------------------------------------
__global__ __launch_bounds__(512, 4) void k_qhkh(
    const float* __restrict__ q, const float* __restrict__ k,
    const float* __restrict__ wq, const float* __restrict__ bq,
    const float* __restrict__ wk, const float* __restrict__ bk,
    float* __restrict__ qh, float* __restrict__ kh)
{
  const int b = blockIdx.y;
  const int chunk = blockIdx.x;           // 32 rows per block
  const int tid = threadIdx.x;
  const int w = tid >> 6;
  const int lane = tid & 63;
  const bool isq = (w >= 4);
  const int hbase = (w & 3) * 4;
  const float* __restrict__ src = isq ? q : k;
  const float* __restrict__ wm  = isq ? wq : wk;
  const float* __restrict__ bm  = isq ? bq : bk;
  float* __restrict__ dst = isq ? qh : kh;

  // lane owns d = 256*j + 4*lane + i  (j,i in 0..3)
  float wreg[4][4][4];
#pragma unroll
  for (int j = 0; j < 4; ++j)
#pragma unroll
    for (int i = 0; i < 4; ++i) {
      const float* wp = wm + (size_t)(256*j + 4*lane + i)*HH + hbase;
#pragma unroll
      for (int hh = 0; hh < 4; ++hh) wreg[j][i][hh] = wp[hh];
    }
  const float mybias = bm[hbase + (lane & 3)];
  const int s0 = chunk * 32;

#pragma unroll 2
  for (int r = 0; r < 32; ++r) {
    const int s = s0 + r;
    const float4* rp = (const float4*)(src + (size_t)(b*SS + s) * DD);
    float4 f[4];
#pragma unroll
    for (int j = 0; j < 4; ++j) f[j] = rp[64*j + lane];
    float a[4] = {0.f, 0.f, 0.f, 0.f};
#pragma unroll
    for (int j = 0; j < 4; ++j) {
      const float fv[4] = {f[j].x, f[j].y, f[j].z, f[j].w};
#pragma unroll
      for (int i = 0; i < 4; ++i)
#pragma unroll
        for (int hh = 0; hh < 4; ++hh)
          a[hh] = fmaf(fv[i], wreg[j][i][hh], a[hh]);
    }
    // interleaved butterfly reduce: lane group (lane&3)==r ends with total of value r
    const int l1 = lane & 1, l2 = lane & 2;
    float u0 = l1 ? a[1] : a[0];  u0 += __shfl_xor(l1 ? a[0] : a[1], 1);
    float u1 = l1 ? a[3] : a[2];  u1 += __shfl_xor(l1 ? a[2] : a[3], 1);
    float red = l2 ? u1 : u0;     red += __shfl_xor(l2 ? u0 : u1, 2);
#pragma unroll
    for (int off = 4; off < 64; off <<= 1) red += __shfl_xor(red, off);
    const float val = red + mybias;
    const float sig = 1.0f / (1.0f + __expf(-val));
    if (lane < 4) dst[(size_t)(b*SS + s)*HH + hbase + lane] = sig;
  }
}

// ---------------------------------------------------------------------------
// K2: kvT partials.  block = (s-chunk of 128 rows, d-chunk of 128, b).
// thread (c = t&31 -> 4 d's, g = t>>5 -> row subset), acc[16][4] in VGPRs,
// LDS-reduce the 8 row-groups, write 16x128 partial (into d_out scratch).
// ---------------------------------------------------------------------------
__global__ __launch_bounds__(256, 4) void k_kvt(
    const float* __restrict__ v, const float* __restrict__ kh,
    float* __restrict__ part)
{
  const int schunk = blockIdx.x;   // 0..31
  const int dchunk = blockIdx.y;   // 0..7
  const int b = blockIdx.z;
  const int t = threadIdx.x;
  const int c = t & 31;
  const int g = t >> 5;
  const int d0 = dchunk*128 + c*4;
  float acc[16][4];
#pragma unroll
  for (int h = 0; h < 16; ++h) {
    acc[h][0] = 0.f; acc[h][1] = 0.f; acc[h][2] = 0.f; acc[h][3] = 0.f;
  }
  const int s0 = schunk * 128;
#pragma unroll 2
  for (int jj = 0; jj < 16; ++jj) {
    const int s = s0 + jj*8 + g;
    const size_t rb = (size_t)(b*SS + s);
    const float4 v4 = *(const float4*)(v + rb*DD + d0);
    const float4* khp = (const float4*)(kh + rb*HH);
    const float4 k0 = khp[0], k1 = khp[1], k2 = khp[2], k3 = khp[3];
    const float kk[16] = {k0.x,k0.y,k0.z,k0.w, k1.x,k1.y,k1.z,k1.w,
                          k2.x,k2.y,k2.z,k2.w, k3.x,k3.y,k3.z,k3.w};
#pragma unroll
    for (int h = 0; h < 16; ++h) {
      acc[h][0] = fmaf(kk[h], v4.x, acc[h][0]);
      acc[h][1] = fmaf(kk[h], v4.y, acc[h][1]);
      acc[h][2] = fmaf(kk[h], v4.z, acc[h][2]);
      acc[h][3] = fmaf(kk[h], v4.w, acc[h][3]);
    }
  }
  __shared__ float lds[8*128];
  const size_t pbase = (size_t)((b*8 + dchunk)*32 + schunk) * 2048;
#pragma unroll   // full unroll: acc indices must stay compile-time (no scratch)
  for (int h = 0; h < 16; ++h) {
    ((float4*)lds)[g*32 + c] = make_float4(acc[h][0], acc[h][1], acc[h][2], acc[h][3]);
    __syncthreads();
    if (t < 128) {
      float sum = 0.f;
#pragma unroll
      for (int gg = 0; gg < 8; ++gg) sum += lds[gg*128 + t];
      part[pbase + h*128 + t] = sum;
    }
    __syncthreads();
  }
}

// ---------------------------------------------------------------------------
// K3: block per (b,h): reduce kvT partials (32 s-chunks) into LDS, compute
// ksum = sum_s kh, then kv[b,h,dv] = sum_d kvT*wv[d, h*64+dv] + ksum*bv.
// ---------------------------------------------------------------------------
__global__ __launch_bounds__(256) void k_kv(
    const float* __restrict__ part, const float* __restrict__ kh,
    const float* __restrict__ wv, const float* __restrict__ bv,
    float* __restrict__ kv)
{
  const int bh = blockIdx.x;
  const int b = bh >> 4, h = bh & 15;
  const int t = threadIdx.x;
  __shared__ float kvt[1024];
  __shared__ float red[256];
#pragma unroll
  for (int m = 0; m < 4; ++m) {
    const int d = t + 256*m;
    const int y = d >> 7, dl = d & 127;
    const size_t base = (size_t)((b*8 + y)*32) * 2048 + h*128 + dl;
    float s = 0.f;
#pragma unroll 4
    for (int x = 0; x < 32; ++x) s += part[base + (size_t)x * 2048];
    kvt[d] = s;
  }
  float ks = 0.f;
  for (int m = 0; m < 16; ++m)
    ks += kh[(size_t)(b*SS + t + 256*m)*HH + h];
  red[t] = ks;
  __syncthreads();
  for (int st = 128; st > 0; st >>= 1) {
    if (t < st) red[t] += red[t + st];
    __syncthreads();
  }
  const float ksum = red[0];
  __syncthreads();   // before reusing red
  const int tsub = t >> 6, dv = t & 63;
  const int col = h*64 + dv;
  float p = 0.f;
#pragma unroll 4
  for (int dd = 0; dd < 256; ++dd) {
    const int d = tsub*256 + dd;
    p = fmaf(kvt[d], wv[(size_t)d*DD + col], p);
  }
  red[t] = p;
  __syncthreads();
  if (t < 64) {
    const float r2 = red[t] + red[64+t] + red[128+t] + red[192+t] + ksum * bv[col];
    kv[(size_t)b*1024 + h*64 + t] = r2;
  }
}

// ---------------------------------------------------------------------------
// K4: block per (b,h): state = cumsum_h kv (head-axis cumsum!), then
// W2[b,h,d] = sum_dv state[dv] * wo[(h*64+dv), d]
// ---------------------------------------------------------------------------
__global__ __launch_bounds__(256) void k_w2(
    const float* __restrict__ kv, const float* __restrict__ wo,
    float* __restrict__ W2)
{
  const int bh = blockIdx.x;
  const int b = bh >> 4, h = bh & 15;
  const int t = threadIdx.x;
  __shared__ float st[64];
  if (t < 64) {
    float s = 0.f;
    for (int hp = 0; hp <= h; ++hp) s += kv[(size_t)b*1024 + hp*64 + t];
    st[t] = s;
  }
  __syncthreads();
  const int d0 = t * 4;
  float4 acc = {0.f, 0.f, 0.f, 0.f};
#pragma unroll 4
  for (int dv = 0; dv < 64; ++dv) {
    const float sv = st[dv];
    const float4 w4 = *(const float4*)(wo + (size_t)(h*64 + dv)*DD + d0);
    acc.x = fmaf(sv, w4.x, acc.x);
    acc.y = fmaf(sv, w4.y, acc.y);
    acc.z = fmaf(sv, w4.z, acc.z);
    acc.w = fmaf(sv, w4.w, acc.w);
  }
  *(float4*)(W2 + (size_t)(b*HH + h)*DD + d0) = acc;
}

// ---------------------------------------------------------------------------
// K5: out[b,s,d] = bo[d] + sum_h qh[b,s,h] * W2[b,h,d]
// thread owns 4 d's; W2[b] register-resident (16 x float4 = 64 VGPR).
// ---------------------------------------------------------------------------
__global__ __launch_bounds__(256, 4) void k_out(
    const float* __restrict__ qh, const float* __restrict__ W2,
    const float* __restrict__ bo, float* __restrict__ out)
{
  const int chunk = blockIdx.x;  // 32 rows per block
  const int b = blockIdx.y;
  const int t = threadIdx.x;
  const int d0 = t * 4;
  float4 w2[16];
#pragma unroll
  for (int h = 0; h < 16; ++h)
    w2[h] = *(const float4*)(W2 + (size_t)(b*HH + h)*DD + d0);
  const float4 bo4 = *(const float4*)(bo + d0);
  __shared__ float qs[32*16];
  const int s0 = chunk * 32;
  {
    const float* srcq = qh + (size_t)(b*SS + s0)*HH;
    qs[t] = srcq[t];
    qs[t + 256] = srcq[t + 256];
  }
  __syncthreads();
#pragma unroll 2
  for (int r = 0; r < 32; ++r) {
    const float4* qr = (const float4*)(qs + r*16);
    const float4 q0 = qr[0], q1 = qr[1], q2 = qr[2], q3 = qr[3];
    const float qv[16] = {q0.x,q0.y,q0.z,q0.w, q1.x,q1.y,q1.z,q1.w,
                          q2.x,q2.y,q2.z,q2.w, q3.x,q3.y,q3.z,q3.w};
    float4 o = bo4;
#pragma unroll
    for (int h = 0; h < 16; ++h) {
      o.x = fmaf(qv[h], w2[h].x, o.x);
      o.y = fmaf(qv[h], w2[h].y, o.y);
      o.z = fmaf(qv[h], w2[h].z, o.z);
      o.w = fmaf(qv[h], w2[h].w, o.w);
    }
    *(float4*)(out + (size_t)(b*SS + s0 + r)*DD + d0) = o;
  }
}

// ---------------------------------------------------------------------------
extern "C" void kernel_launch(void* const* d_in, const int* in_sizes, int n_in,
                              void* d_out, int out_size, void* d_ws, size_t ws_size,
                              hipStream_t stream)
{
  const float* q  = (const float*)d_in[0];
  const float* k  = (const float*)d_in[1];
  const float* v  = (const float*)d_in[2];
  const float* wq = (const float*)d_in[3];
  const float* bq = (const float*)d_in[4];
  const float* wk = (const float*)d_in[5];
  const float* bk = (const float*)d_in[6];
  const float* wv = (const float*)d_in[7];
  const float* bv = (const float*)d_in[8];
  const float* wo = (const float*)d_in[9];
  const float* bo = (const float*)d_in[10];
  float* out = (float*)d_out;
  float* ws  = (float*)d_ws;

  // d_ws layout (floats): qh 262144 | kh 262144 | kv 4096 | W2 65536  (~2.3 MB)
  float* qh = ws;
  float* kh = ws + 262144;
  float* kv = ws + 524288;
  float* W2 = ws + 528384;
  // kvT partials (1024 blocks * 2048 floats = 8 MB) live at the FRONT of
  // d_out: consumed by k_kv, fully overwritten by k_out afterwards.
  float* part = out;

  hipLaunchKernelGGL(k_qhkh, dim3(128, 4), dim3(512), 0, stream,
                     q, k, wq, bq, wk, bk, qh, kh);
  hipLaunchKernelGGL(k_kvt, dim3(32, 8, 4), dim3(256), 0, stream,
                     v, kh, part);
  hipLaunchKernelGGL(k_kv, dim3(64), dim3(256), 0, stream,
                     part, kh, wv, bv, kv);
  hipLaunchKernelGGL(k_w2, dim3(64), dim3(256), 0, stream,
                     kv, wo, W2);
  hipLaunchKernelGGL(k_out, dim3(128, 4), dim3(256), 0, stream,
                     qh, W2, bo, out);
}

// Round 4
// 131.773 us; speedup vs baseline: 2.2967x; 2.2967x over previous
//
#include <hip/hip_runtime.h>

#define BB 4
#define SS 4096
#define DD 1024
#define HH 16

typedef float nfloat4 __attribute__((ext_vector_type(4)));

// ---------------------------------------------------------------------------
// K1: qh = sigmoid(q@wq+bq), kh = sigmoid(k@wk+bk)   (B,S,H) each
// 512 threads: waves 0-3 -> k, 4-7 -> q; each wave owns 4 heads.
// Row mapping s = r*128 + chunk: at instant r, the 128 blocks of batch b read
// 128 CONSECUTIVE rows (512KB contiguous) -> HBM channels hit uniformly.
// ---------------------------------------------------------------------------
__global__ __launch_bounds__(512, 4) void k_qhkh(
    const float* __restrict__ q, const float* __restrict__ k,
    const float* __restrict__ wq, const float* __restrict__ bq,
    const float* __restrict__ wk, const float* __restrict__ bk,
    float* __restrict__ qh, float* __restrict__ kh)
{
  const int b = blockIdx.y;
  const int chunk = blockIdx.x;           // 0..127
  const int tid = threadIdx.x;
  const int w = tid >> 6;
  const int lane = tid & 63;
  const bool isq = (w >= 4);
  const int hbase = (w & 3) * 4;
  const float* __restrict__ src = isq ? q : k;
  const float* __restrict__ wm  = isq ? wq : wk;
  const float* __restrict__ bm  = isq ? bq : bk;
  float* __restrict__ dst = isq ? qh : kh;

  // lane owns d = 256*j + 4*lane + i  (j,i in 0..3)
  float wreg[4][4][4];
#pragma unroll
  for (int j = 0; j < 4; ++j)
#pragma unroll
    for (int i = 0; i < 4; ++i) {
      const float* wp = wm + (size_t)(256*j + 4*lane + i)*HH + hbase;
#pragma unroll
      for (int hh = 0; hh < 4; ++hh) wreg[j][i][hh] = wp[hh];
    }
  const float mybias = bm[hbase + (lane & 3)];

#pragma unroll 2
  for (int r = 0; r < 32; ++r) {
    const int s = r * 128 + chunk;        // block-interleaved rows
    const float4* rp = (const float4*)(src + (size_t)(b*SS + s) * DD);
    float4 f[4];
#pragma unroll
    for (int j = 0; j < 4; ++j) f[j] = rp[64*j + lane];
    float a[4] = {0.f, 0.f, 0.f, 0.f};
#pragma unroll
    for (int j = 0; j < 4; ++j) {
      const float fv[4] = {f[j].x, f[j].y, f[j].z, f[j].w};
#pragma unroll
      for (int i = 0; i < 4; ++i)
#pragma unroll
        for (int hh = 0; hh < 4; ++hh)
          a[hh] = fmaf(fv[i], wreg[j][i][hh], a[hh]);
    }
    // interleaved butterfly reduce: lane group (lane&3) ends with head hbase+(lane&3)
    const int l1 = lane & 1, l2 = lane & 2;
    float u0 = l1 ? a[1] : a[0];  u0 += __shfl_xor(l1 ? a[0] : a[1], 1);
    float u1 = l1 ? a[3] : a[2];  u1 += __shfl_xor(l1 ? a[2] : a[3], 1);
    float red = l2 ? u1 : u0;     red += __shfl_xor(l2 ? u0 : u1, 2);
#pragma unroll
    for (int off = 4; off < 64; off <<= 1) red += __shfl_xor(red, off);
    const float val = red + mybias;
    const float sig = 1.0f / (1.0f + __expf(-val));
    if (lane < 4) dst[(size_t)(b*SS + s)*HH + hbase + lane] = sig;
  }
}

// ---------------------------------------------------------------------------
// K2: kvT partials.  Block (schunk, dchunk, b); thread (c = t&31 -> 4 d's,
// g = t>>5). Row mapping s = (jj*8+g)*32 + schunk: at instant jj, all blocks
// together read 256 consecutive rows, full width across dchunks.
// Partials go into d_out scratch (overwritten by k_out at the end).
// ---------------------------------------------------------------------------
__global__ __launch_bounds__(256, 4) void k_kvt(
    const float* __restrict__ v, const float* __restrict__ kh,
    float* __restrict__ part)
{
  const int schunk = blockIdx.x;   // 0..31
  const int dchunk = blockIdx.y;   // 0..7
  const int b = blockIdx.z;
  const int t = threadIdx.x;
  const int c = t & 31;
  const int g = t >> 5;
  const int d0 = dchunk*128 + c*4;
  float acc[16][4];
#pragma unroll
  for (int h = 0; h < 16; ++h) {
    acc[h][0] = 0.f; acc[h][1] = 0.f; acc[h][2] = 0.f; acc[h][3] = 0.f;
  }
#pragma unroll 2
  for (int jj = 0; jj < 16; ++jj) {
    const int s = (jj*8 + g)*32 + schunk;   // block-interleaved rows
    const size_t rb = (size_t)(b*SS + s);
    const float4 v4 = *(const float4*)(v + rb*DD + d0);
    const float4* khp = (const float4*)(kh + rb*HH);
    const float4 k0 = khp[0], k1 = khp[1], k2 = khp[2], k3 = khp[3];
    const float kk[16] = {k0.x,k0.y,k0.z,k0.w, k1.x,k1.y,k1.z,k1.w,
                          k2.x,k2.y,k2.z,k2.w, k3.x,k3.y,k3.z,k3.w};
#pragma unroll
    for (int h = 0; h < 16; ++h) {
      acc[h][0] = fmaf(kk[h], v4.x, acc[h][0]);
      acc[h][1] = fmaf(kk[h], v4.y, acc[h][1]);
      acc[h][2] = fmaf(kk[h], v4.z, acc[h][2]);
      acc[h][3] = fmaf(kk[h], v4.w, acc[h][3]);
    }
  }
  __shared__ float lds[8*128];
  const size_t pbase = (size_t)((b*8 + dchunk)*32 + schunk) * 2048;
#pragma unroll   // full unroll: acc indices stay compile-time
  for (int h = 0; h < 16; ++h) {
    ((float4*)lds)[g*32 + c] = make_float4(acc[h][0], acc[h][1], acc[h][2], acc[h][3]);
    __syncthreads();
    if (t < 128) {
      float sum = 0.f;
#pragma unroll
      for (int gg = 0; gg < 8; ++gg) sum += lds[gg*128 + t];
      part[pbase + h*128 + t] = sum;
    }
    __syncthreads();
  }
}

// ---------------------------------------------------------------------------
// K3: reduce part over the 32 schunks -> kvt[b][h][1024] (coalesced 1KB wave
// reads), plus ksum partials from kh. Grid (8 dchunk, 4 b).
// ---------------------------------------------------------------------------
__global__ __launch_bounds__(256, 4) void k_red(
    const float* __restrict__ part, const float* __restrict__ kh,
    float* __restrict__ kvt, float* __restrict__ ksump)
{
  const int dchunk = blockIdx.x;
  const int b = blockIdx.y;
  const int t = threadIdx.x;
  const size_t pb = (size_t)((b*8 + dchunk)*32) * 2048;
#pragma unroll
  for (int ho = 0; ho < 8; ++ho) {
    float s = 0.f;
#pragma unroll 4
    for (int sc = 0; sc < 32; ++sc)
      s += part[pb + (size_t)sc*2048 + ho*256 + t];
    const int h = ho*2 + (t >> 7), dl = t & 127;
    kvt[(size_t)(b*16 + h)*1024 + dchunk*128 + dl] = s;
  }
  // ksum partial over this dchunk's 512 rows (thread t holds head t&15)
  float ks = 0.f;
  const size_t kb = (size_t)(b*SS + dchunk*512) * HH;
#pragma unroll 4
  for (int m = 0; m < 32; ++m)
    ks += kh[kb + m*256 + t];
  __shared__ float red[256];
  red[t] = ks;
  __syncthreads();
#pragma unroll
  for (int st = 128; st >= 16; st >>= 1) {
    if (t < st) red[t] += red[t + st];
    __syncthreads();
  }
  if (t < 16) ksump[(b*8 + dchunk)*16 + t] = red[t];
}

// ---------------------------------------------------------------------------
// K4: per (b,h): kv[b,h,dv] = sum_d kvt[b,h,d]*wv[d, h*64+dv] + ksum*bv.
// (cumsum must happen on kv BEFORE the wo contraction -- done in k_w2.)
// ---------------------------------------------------------------------------
__global__ __launch_bounds__(256, 2) void k_kv(
    const float* __restrict__ kvt, const float* __restrict__ ksump,
    const float* __restrict__ wv, const float* __restrict__ bv,
    float* __restrict__ kv)
{
  const int h = blockIdx.x;    // 0..15  (cols h*64..h*64+63 of wv)
  const int b = blockIdx.y;
  const int t = threadIdx.x;
  const int dg = t >> 6, c = t & 63;
  const float* kp = kvt + (size_t)(b*16 + h)*1024 + dg*256;
  const float* wp = wv + (size_t)(dg*256)*DD + h*64 + c;
  float p = 0.f;
#pragma unroll 4
  for (int dd = 0; dd < 256; ++dd)
    p = fmaf(kp[dd], wp[(size_t)dd*DD], p);
  __shared__ float red[256];
  red[t] = p;
  __syncthreads();
  if (t < 64) {
    float ks = 0.f;
#pragma unroll
    for (int dc = 0; dc < 8; ++dc) ks += ksump[(b*8 + dc)*16 + h];
    kv[(size_t)b*1024 + h*64 + t] =
        red[t] + red[64+t] + red[128+t] + red[192+t] + ks * bv[h*64 + t];
  }
}

// ---------------------------------------------------------------------------
// K5: per (b,h): state = cumsum_h kv (HEAD-axis cumsum), then
// W2[b,h,d] = sum_dv state[dv] * wo[(h*64+dv), d]   (verified in round 1)
// ---------------------------------------------------------------------------
__global__ __launch_bounds__(256) void k_w2(
    const float* __restrict__ kv, const float* __restrict__ wo,
    float* __restrict__ W2)
{
  const int bh = blockIdx.x;
  const int b = bh >> 4, h = bh & 15;
  const int t = threadIdx.x;
  __shared__ float st[64];
  if (t < 64) {
    float s = 0.f;
    for (int hp = 0; hp <= h; ++hp) s += kv[(size_t)b*1024 + hp*64 + t];
    st[t] = s;
  }
  __syncthreads();
  const int d0 = t * 4;
  float4 acc = {0.f, 0.f, 0.f, 0.f};
#pragma unroll 4
  for (int dv = 0; dv < 64; ++dv) {
    const float sv = st[dv];
    const float4 w4 = *(const float4*)(wo + (size_t)(h*64 + dv)*DD + d0);
    acc.x = fmaf(sv, w4.x, acc.x);
    acc.y = fmaf(sv, w4.y, acc.y);
    acc.z = fmaf(sv, w4.z, acc.z);
    acc.w = fmaf(sv, w4.w, acc.w);
  }
  *(float4*)(W2 + (size_t)(b*HH + h)*DD + d0) = acc;
}

// ---------------------------------------------------------------------------
// K6: out[b,s,:] = bo + sum_h qh[b,s,h] * W2[b,h,:]
// 2048 blocks x 8 rows; row mapping s = r*512 + bx -> at instant r the grid
// writes 512 consecutive rows (2MB contiguous per b). Nontemporal stores.
// ---------------------------------------------------------------------------
__global__ __launch_bounds__(256, 4) void k_out(
    const float* __restrict__ qh, const float* __restrict__ W2,
    const float* __restrict__ bo, float* __restrict__ out)
{
  const int bx = blockIdx.x;   // 0..511
  const int b = blockIdx.y;
  const int t = threadIdx.x;
  const int d0 = t * 4;
  float4 w2[16];
#pragma unroll
  for (int h = 0; h < 16; ++h)
    w2[h] = *(const float4*)(W2 + (size_t)(b*HH + h)*DD + d0);
  const float4 bo4 = *(const float4*)(bo + d0);
  __shared__ float qs[128];
  if (t < 128)
    qs[t] = qh[(size_t)(b*SS + (t>>4)*512 + bx)*HH + (t & 15)];
  __syncthreads();
#pragma unroll
  for (int r = 0; r < 8; ++r) {
    const float4* qr = (const float4*)(qs + r*16);
    const float4 q0 = qr[0], q1 = qr[1], q2 = qr[2], q3 = qr[3];
    const float qv[16] = {q0.x,q0.y,q0.z,q0.w, q1.x,q1.y,q1.z,q1.w,
                          q2.x,q2.y,q2.z,q2.w, q3.x,q3.y,q3.z,q3.w};
    float4 o = bo4;
#pragma unroll
    for (int h = 0; h < 16; ++h) {
      o.x = fmaf(qv[h], w2[h].x, o.x);
      o.y = fmaf(qv[h], w2[h].y, o.y);
      o.z = fmaf(qv[h], w2[h].z, o.z);
      o.w = fmaf(qv[h], w2[h].w, o.w);
    }
    nfloat4 ov = { o.x, o.y, o.z, o.w };
    nfloat4* dst = (nfloat4*)(out + (size_t)(b*SS + r*512 + bx)*DD + d0);
    __builtin_nontemporal_store(ov, dst);
  }
}

// ---------------------------------------------------------------------------
extern "C" void kernel_launch(void* const* d_in, const int* in_sizes, int n_in,
                              void* d_out, int out_size, void* d_ws, size_t ws_size,
                              hipStream_t stream)
{
  const float* q  = (const float*)d_in[0];
  const float* k  = (const float*)d_in[1];
  const float* v  = (const float*)d_in[2];
  const float* wq = (const float*)d_in[3];
  const float* bq = (const float*)d_in[4];
  const float* wk = (const float*)d_in[5];
  const float* bk = (const float*)d_in[6];
  const float* wv = (const float*)d_in[7];
  const float* bv = (const float*)d_in[8];
  const float* wo = (const float*)d_in[9];
  const float* bo = (const float*)d_in[10];
  float* out = (float*)d_out;
  float* ws  = (float*)d_ws;

  // ws layout (floats):
  // qh 262144 | kh 262144 | kvt 65536 | ksump 512 | kv 4096 | W2 65536
  float* qh    = ws;
  float* kh    = ws + 262144;
  float* kvt   = ws + 524288;
  float* ksump = ws + 589824;
  float* kv    = ws + 590336;
  float* W2    = ws + 594432;
  // kvT partials (1024 blocks * 2048 floats = 8 MB) at the FRONT of d_out:
  // consumed by k_red, fully overwritten by k_out afterwards.
  float* part = out;

  hipLaunchKernelGGL(k_qhkh, dim3(128, 4), dim3(512), 0, stream,
                     q, k, wq, bq, wk, bk, qh, kh);
  hipLaunchKernelGGL(k_kvt, dim3(32, 8, 4), dim3(256), 0, stream,
                     v, kh, part);
  hipLaunchKernelGGL(k_red, dim3(8, 4), dim3(256), 0, stream,
                     part, kh, kvt, ksump);
  hipLaunchKernelGGL(k_kv, dim3(16, 4), dim3(256), 0, stream,
                     kvt, ksump, wv, bv, kv);
  hipLaunchKernelGGL(k_w2, dim3(64), dim3(256), 0, stream,
                     kv, wo, W2);
  hipLaunchKernelGGL(k_out, dim3(512, 4), dim3(256), 0, stream,
                     qh, W2, bo, out);
}

// Round 5
// 121.274 us; speedup vs baseline: 2.4955x; 1.0866x over previous
//
#include <hip/hip_runtime.h>

#define BB 4
#define SS 4096
#define DD 1024
#define HH 16

typedef float nfloat4 __attribute__((ext_vector_type(4)));

// ---------------------------------------------------------------------------
// K1: qh = sigmoid(q@wq+bq), kh = sigmoid(k@wk+bk)   (B,S,H) each
// 512 threads: waves 0-3 -> k, 4-7 -> q; each wave owns 4 heads.
// Grid (256,4): 16 rows/block, s = r*256 + chunk -> at instant r the grid
// reads 256 consecutive rows. Explicit ping-pong prefetch: row r+1's loads
// are in flight while row r computes.
// ---------------------------------------------------------------------------
__global__ __launch_bounds__(512, 4) void k_qhkh(
    const float* __restrict__ q, const float* __restrict__ k,
    const float* __restrict__ wq, const float* __restrict__ bq,
    const float* __restrict__ wk, const float* __restrict__ bk,
    float* __restrict__ qh, float* __restrict__ kh)
{
  const int b = blockIdx.y;
  const int chunk = blockIdx.x;           // 0..255
  const int tid = threadIdx.x;
  const int w = tid >> 6;
  const int lane = tid & 63;
  const bool isq = (w >= 4);
  const int hbase = (w & 3) * 4;
  const float* __restrict__ src = isq ? q : k;
  const float* __restrict__ wm  = isq ? wq : wk;
  const float* __restrict__ bm  = isq ? bq : bk;
  float* __restrict__ dst = isq ? qh : kh;

  // lane owns d = 256*j + 4*lane + i  (j,i in 0..3)
  float wreg[4][4][4];
#pragma unroll
  for (int j = 0; j < 4; ++j)
#pragma unroll
    for (int i = 0; i < 4; ++i) {
      const float* wp = wm + (size_t)(256*j + 4*lane + i)*HH + hbase;
#pragma unroll
      for (int hh = 0; hh < 4; ++hh) wreg[j][i][hh] = wp[hh];
    }
  const float mybias = bm[hbase + (lane & 3)];

  const float4* base = (const float4*)(src + (size_t)b*SS*DD) + lane;

  auto loadrow = [&](float4* f, int r) {
    const float4* rp = base + (size_t)(r*256 + chunk)*256;
    f[0] = rp[0]; f[1] = rp[64]; f[2] = rp[128]; f[3] = rp[192];
  };
  auto compute = [&](const float4* f, int r) {
    float a[4] = {0.f, 0.f, 0.f, 0.f};
#pragma unroll
    for (int j = 0; j < 4; ++j) {
      const float fv[4] = {f[j].x, f[j].y, f[j].z, f[j].w};
#pragma unroll
      for (int i = 0; i < 4; ++i)
#pragma unroll
        for (int hh = 0; hh < 4; ++hh)
          a[hh] = fmaf(fv[i], wreg[j][i][hh], a[hh]);
    }
    // interleaved butterfly reduce: lane group (lane&3) -> head hbase+(lane&3)
    const int l1 = lane & 1, l2 = lane & 2;
    float u0 = l1 ? a[1] : a[0];  u0 += __shfl_xor(l1 ? a[0] : a[1], 1);
    float u1 = l1 ? a[3] : a[2];  u1 += __shfl_xor(l1 ? a[2] : a[3], 1);
    float red = l2 ? u1 : u0;     red += __shfl_xor(l2 ? u0 : u1, 2);
#pragma unroll
    for (int off = 4; off < 64; off <<= 1) red += __shfl_xor(red, off);
    const float val = red + mybias;
    const float sig = 1.0f / (1.0f + __expf(-val));
    if (lane < 4)
      dst[(size_t)(b*SS + r*256 + chunk)*HH + hbase + lane] = sig;
  };

  float4 f0[4], f1[4];
  loadrow(f0, 0);
#pragma unroll
  for (int rr = 0; rr < 16; rr += 2) {
    loadrow(f1, rr + 1);
    compute(f0, rr);
    if (rr + 2 < 16) loadrow(f0, rr + 2);
    compute(f1, rr + 1);
  }
}

// ---------------------------------------------------------------------------
// K2: kvT partials.  Grid (64 schunk, 8 dchunk, 4 b) = 2048 blocks.
// Thread (c = t&31 -> 4 d's, hh2 = (t>>5)&1 -> head half, g = t>>6 -> row
// group). acc[8][4] (~32 VGPR) -> 8 waves/SIMD occupancy.
// Row mapping s = (jj*4+g)*64 + schunk: concurrent blocks read 256
// consecutive rows. Partials into d_out scratch (16 MB).
// ---------------------------------------------------------------------------
__global__ __launch_bounds__(256, 8) void k_kvt(
    const float* __restrict__ v, const float* __restrict__ kh,
    float* __restrict__ part)
{
  const int schunk = blockIdx.x;   // 0..63
  const int dchunk = blockIdx.y;   // 0..7
  const int b = blockIdx.z;
  const int t = threadIdx.x;
  const int c = t & 31;
  const int hh2 = (t >> 5) & 1;
  const int g = t >> 6;            // 0..3
  const int d0 = dchunk*128 + c*4;
  float acc[8][4];
#pragma unroll
  for (int h = 0; h < 8; ++h) {
    acc[h][0] = 0.f; acc[h][1] = 0.f; acc[h][2] = 0.f; acc[h][3] = 0.f;
  }
#pragma unroll 2
  for (int jj = 0; jj < 16; ++jj) {
    const int s = (jj*4 + g)*64 + schunk;
    const size_t rb = (size_t)(b*SS + s);
    const float4 v4 = *(const float4*)(v + rb*DD + d0);
    const float4* khp = (const float4*)(kh + rb*HH) + hh2*2;
    const float4 k0 = khp[0], k1 = khp[1];
    const float kk[8] = {k0.x,k0.y,k0.z,k0.w, k1.x,k1.y,k1.z,k1.w};
#pragma unroll
    for (int h = 0; h < 8; ++h) {
      acc[h][0] = fmaf(kk[h], v4.x, acc[h][0]);
      acc[h][1] = fmaf(kk[h], v4.y, acc[h][1]);
      acc[h][2] = fmaf(kk[h], v4.z, acc[h][2]);
      acc[h][3] = fmaf(kk[h], v4.w, acc[h][3]);
    }
  }
  __shared__ float lds[4][2][128];
  const size_t pbase = (size_t)((b*8 + dchunk)*64 + schunk) * 2048;
#pragma unroll   // full unroll: acc indices stay compile-time
  for (int h = 0; h < 8; ++h) {
    *(float4*)&lds[g][hh2][c*4] =
        make_float4(acc[h][0], acc[h][1], acc[h][2], acc[h][3]);
    __syncthreads();
    {
      const int hh2r = t >> 7, dl = t & 127;
      const float sum = lds[0][hh2r][dl] + lds[1][hh2r][dl]
                      + lds[2][hh2r][dl] + lds[3][hh2r][dl];
      part[pbase + (hh2r*8 + h)*128 + dl] = sum;
    }
    __syncthreads();
  }
}

// ---------------------------------------------------------------------------
// K3: reduce part over the 64 schunks -> kvt[b][h][1024].
// Grid (8 dchunk, 4 b, 4 head-quarter) = 128 blocks, fully coalesced reads.
// ---------------------------------------------------------------------------
__global__ __launch_bounds__(256, 8) void k_red(
    const float* __restrict__ part, float* __restrict__ kvt)
{
  const int dchunk = blockIdx.x;
  const int b = blockIdx.y;
  const int hq = blockIdx.z;       // 0..3
  const int t = threadIdx.x;
  const size_t pb = (size_t)((b*8 + dchunk)*64) * 2048;
#pragma unroll
  for (int ho = 0; ho < 2; ++ho) {
    const int h = hq*4 + ho*2 + (t >> 7), dl = t & 127;
    float s = 0.f;
#pragma unroll 8
    for (int sc = 0; sc < 64; ++sc)
      s += part[pb + (size_t)sc*2048 + h*128 + dl];
    kvt[(size_t)(b*16 + h)*1024 + dchunk*128 + dl] = s;
  }
}

// ---------------------------------------------------------------------------
// K4: per (b,h): kv[b,h,dv] = sum_d kvt[b,h,d]*wv[d, h*64+dv] + ksum*bv,
// ksum = sum_s kh[b,s,h] computed in-block (L2-resident column reads).
// ---------------------------------------------------------------------------
__global__ __launch_bounds__(256, 2) void k_kv(
    const float* __restrict__ kvt, const float* __restrict__ kh,
    const float* __restrict__ wv, const float* __restrict__ bv,
    float* __restrict__ kv)
{
  const int h = blockIdx.x;    // 0..15
  const int b = blockIdx.y;
  const int t = threadIdx.x;
  const int dg = t >> 6, c = t & 63;
  const float* kp = kvt + (size_t)(b*16 + h)*1024 + dg*256;
  const float* wp = wv + (size_t)(dg*256)*DD + h*64 + c;
  float p = 0.f;
#pragma unroll 4
  for (int dd = 0; dd < 256; ++dd)
    p = fmaf(kp[dd], wp[(size_t)dd*DD], p);
  float ks = 0.f;
#pragma unroll 4
  for (int m = 0; m < 16; ++m)
    ks += kh[(size_t)(b*SS + m*256 + t)*HH + h];
  __shared__ float red[256], redk[256];
  red[t] = p; redk[t] = ks;
  __syncthreads();
  if (t < 128) redk[t] += redk[t + 128];
  __syncthreads();
  if (t < 64) redk[t] += redk[t + 64];
  __syncthreads();
  if (t < 64) {
    float kst = redk[t];
#pragma unroll
    for (int off = 32; off > 0; off >>= 1) kst += __shfl_xor(kst, off);
    const float psum = red[t] + red[64+t] + red[128+t] + red[192+t];
    kv[(size_t)b*1024 + h*64 + t] = psum + kst * bv[h*64 + t];
  }
}

// ---------------------------------------------------------------------------
// K5: per (b,h): state = cumsum_h kv (HEAD-axis cumsum), then
// W2[b,h,d] = sum_dv state[dv] * wo[(h*64+dv), d]
// ---------------------------------------------------------------------------
__global__ __launch_bounds__(256) void k_w2(
    const float* __restrict__ kv, const float* __restrict__ wo,
    float* __restrict__ W2)
{
  const int bh = blockIdx.x;
  const int b = bh >> 4, h = bh & 15;
  const int t = threadIdx.x;
  __shared__ float st[64];
  if (t < 64) {
    float s = 0.f;
    for (int hp = 0; hp <= h; ++hp) s += kv[(size_t)b*1024 + hp*64 + t];
    st[t] = s;
  }
  __syncthreads();
  const int d0 = t * 4;
  float4 acc = {0.f, 0.f, 0.f, 0.f};
#pragma unroll 4
  for (int dv = 0; dv < 64; ++dv) {
    const float sv = st[dv];
    const float4 w4 = *(const float4*)(wo + (size_t)(h*64 + dv)*DD + d0);
    acc.x = fmaf(sv, w4.x, acc.x);
    acc.y = fmaf(sv, w4.y, acc.y);
    acc.z = fmaf(sv, w4.z, acc.z);
    acc.w = fmaf(sv, w4.w, acc.w);
  }
  *(float4*)(W2 + (size_t)(b*HH + h)*DD + d0) = acc;
}

// ---------------------------------------------------------------------------
// K6: out[b,s,:] = bo + sum_h qh[b,s,h] * W2[b,h,:]
// 2048 blocks x 8 rows; s = r*512 + bx -> 512 consecutive rows concurrent.
// Nontemporal stores.
// ---------------------------------------------------------------------------
__global__ __launch_bounds__(256, 4) void k_out(
    const float* __restrict__ qh, const float* __restrict__ W2,
    const float* __restrict__ bo, float* __restrict__ out)
{
  const int bx = blockIdx.x;   // 0..511
  const int b = blockIdx.y;
  const int t = threadIdx.x;
  const int d0 = t * 4;
  float4 w2[16];
#pragma unroll
  for (int h = 0; h < 16; ++h)
    w2[h] = *(const float4*)(W2 + (size_t)(b*HH + h)*DD + d0);
  const float4 bo4 = *(const float4*)(bo + d0);
  __shared__ float qs[128];
  if (t < 128)
    qs[t] = qh[(size_t)(b*SS + (t>>4)*512 + bx)*HH + (t & 15)];
  __syncthreads();
#pragma unroll
  for (int r = 0; r < 8; ++r) {
    const float4* qr = (const float4*)(qs + r*16);
    const float4 q0 = qr[0], q1 = qr[1], q2 = qr[2], q3 = qr[3];
    const float qv[16] = {q0.x,q0.y,q0.z,q0.w, q1.x,q1.y,q1.z,q1.w,
                          q2.x,q2.y,q2.z,q2.w, q3.x,q3.y,q3.z,q3.w};
    float4 o = bo4;
#pragma unroll
    for (int h = 0; h < 16; ++h) {
      o.x = fmaf(qv[h], w2[h].x, o.x);
      o.y = fmaf(qv[h], w2[h].y, o.y);
      o.z = fmaf(qv[h], w2[h].z, o.z);
      o.w = fmaf(qv[h], w2[h].w, o.w);
    }
    nfloat4 ov = { o.x, o.y, o.z, o.w };
    nfloat4* dst = (nfloat4*)(out + (size_t)(b*SS + r*512 + bx)*DD + d0);
    __builtin_nontemporal_store(ov, dst);
  }
}

// ---------------------------------------------------------------------------
extern "C" void kernel_launch(void* const* d_in, const int* in_sizes, int n_in,
                              void* d_out, int out_size, void* d_ws, size_t ws_size,
                              hipStream_t stream)
{
  const float* q  = (const float*)d_in[0];
  const float* k  = (const float*)d_in[1];
  const float* v  = (const float*)d_in[2];
  const float* wq = (const float*)d_in[3];
  const float* bq = (const float*)d_in[4];
  const float* wk = (const float*)d_in[5];
  const float* bk = (const float*)d_in[6];
  const float* wv = (const float*)d_in[7];
  const float* bv = (const float*)d_in[8];
  const float* wo = (const float*)d_in[9];
  const float* bo = (const float*)d_in[10];
  float* out = (float*)d_out;
  float* ws  = (float*)d_ws;

  // ws layout (floats): qh 262144 | kh 262144 | kvt 65536 | kv 4096 | W2 65536
  float* qh  = ws;
  float* kh  = ws + 262144;
  float* kvt = ws + 524288;
  float* kv  = ws + 589824;
  float* W2  = ws + 593920;
  // kvT partials (2048 blocks * 2048 floats = 16 MB) at the FRONT of d_out:
  // consumed by k_red, fully overwritten by k_out afterwards.
  float* part = out;

  hipLaunchKernelGGL(k_qhkh, dim3(256, 4), dim3(512), 0, stream,
                     q, k, wq, bq, wk, bk, qh, kh);
  hipLaunchKernelGGL(k_kvt, dim3(64, 8, 4), dim3(256), 0, stream,
                     v, kh, part);
  hipLaunchKernelGGL(k_red, dim3(8, 4, 4), dim3(256), 0, stream,
                     part, kvt);
  hipLaunchKernelGGL(k_kv, dim3(16, 4), dim3(256), 0, stream,
                     kvt, kh, wv, bv, kv);
  hipLaunchKernelGGL(k_w2, dim3(64), dim3(256), 0, stream,
                     kv, wo, W2);
  hipLaunchKernelGGL(k_out, dim3(512, 4), dim3(256), 0, stream,
                     qh, W2, bo, out);
}

// Round 6
// 108.207 us; speedup vs baseline: 2.7969x; 1.1208x over previous
//
#include <hip/hip_runtime.h>

#define SS 4096
#define DD 1024
#define HH 16

typedef float nfloat4 __attribute__((ext_vector_type(4)));
typedef __attribute__((ext_vector_type(8))) short bf16x8;
typedef __attribute__((ext_vector_type(4))) float f32x4;

__device__ __forceinline__ short f2bf(float f) {
  union { float f; unsigned u; } z; z.f = f;
  return (short)((z.u + 0x8000u) >> 16);    // round-half-up to bf16
}

// ---------------------------------------------------------------------------
// K0: pre-pack wq,wk into MFMA A-fragment order, bf16.
// wf[m][t][lane][e] = w_m[t*32 + (lane>>4)*8 + e][lane&15]
// (A-tile = 16 heads x 32 k; same (g,e)->k bijection as the q-side B loads,
// so the MFMA contraction is layout-bijection-invariant.)
// ---------------------------------------------------------------------------
__global__ __launch_bounds__(256) void k_wfrag(
    const float* __restrict__ wq, const float* __restrict__ wk,
    short* __restrict__ wf)
{
  const int m = blockIdx.x;                 // 0=q, 1=k
  const float* __restrict__ w = m ? wk : wq;
  short* __restrict__ dst = wf + m * 16384;
  for (int p = threadIdx.x; p < 2048; p += 256) {   // p = t*64 + lane
    const int t = p >> 6, l = p & 63;
    const int kbase = t*32 + ((l >> 4) * 8), col = l & 15;
    short v[8];
#pragma unroll
    for (int e = 0; e < 8; ++e)
      v[e] = f2bf(w[(size_t)(kbase + e)*HH + col]);
    short* o = dst + (size_t)p * 8;
#pragma unroll
    for (int e = 0; e < 8; ++e) o[e] = v[e];
  }
}

// ---------------------------------------------------------------------------
// K1: qh = sigmoid(q@wq+bq), kh = sigmoid(k@wk+bk) via MFMA 16x16x32 bf16.
// One wave = one 16-row tile (K=1024 in 32 MFMA steps). No LDS, no barriers,
// no cross-lane reduce. D = A(w: 16h x 32k) * B(x^T: 32k x 16rows):
// C/D layout col=lane&15 -> q-row, row=(lane>>4)*4+reg -> head
// => per-lane float4 store, wave store = 1KB contiguous.
// ---------------------------------------------------------------------------
__global__ __launch_bounds__(256, 2) void k_qhkh(
    const float* __restrict__ q, const float* __restrict__ k,
    const short* __restrict__ wf,
    const float* __restrict__ bq, const float* __restrict__ bk,
    float* __restrict__ qh, float* __restrict__ kh)
{
  const int wid = threadIdx.x >> 6, lane = threadIdx.x & 63;
  const int tile = blockIdx.x * 4 + wid;     // 0..2047
  const bool isk = tile >= 1024;
  const int t16 = isk ? (tile - 1024) : tile;
  const float* __restrict__ src = isk ? k : q;
  const short* __restrict__ wfm = wf + (isk ? 16384 : 0);
  const float* __restrict__ bias = isk ? bk : bq;
  float* __restrict__ dst = isk ? kh : qh;
  const int s0 = t16 * 16;                   // flat row over (B,S)
  const int row = lane & 15, g = lane >> 4;
  const float* __restrict__ xrow = src + (size_t)(s0 + row) * DD + g * 8;
  f32x4 acc = {0.f, 0.f, 0.f, 0.f};
#pragma unroll 8
  for (int t = 0; t < 32; ++t) {
    const bf16x8 a = *(const bf16x8*)(wfm + (size_t)(t*64 + lane) * 8);
    const float4 x0 = *(const float4*)(xrow + t*32);
    const float4 x1 = *(const float4*)(xrow + t*32 + 4);
    bf16x8 bb;
    bb[0]=f2bf(x0.x); bb[1]=f2bf(x0.y); bb[2]=f2bf(x0.z); bb[3]=f2bf(x0.w);
    bb[4]=f2bf(x1.x); bb[5]=f2bf(x1.y); bb[6]=f2bf(x1.z); bb[7]=f2bf(x1.w);
    acc = __builtin_amdgcn_mfma_f32_16x16x32_bf16(a, bb, acc, 0, 0, 0);
  }
  const float4 b4 = ((const float4*)bias)[g];
  float4 o;
  o.x = 1.f/(1.f + __expf(-(acc[0] + b4.x)));
  o.y = 1.f/(1.f + __expf(-(acc[1] + b4.y)));
  o.z = 1.f/(1.f + __expf(-(acc[2] + b4.z)));
  o.w = 1.f/(1.f + __expf(-(acc[3] + b4.w)));
  *(float4*)(dst + (size_t)(s0 + row)*HH + g*4) = o;
}

// ---------------------------------------------------------------------------
// K2: kvT partials.  Grid (64 schunk, 8 dchunk, 4 b) = 2048 blocks.
// Thread (c = t&31 -> 4 d's, hh2 = (t>>5)&1 -> head half, g = t>>6 -> row
// group). acc[8][4] (~32 VGPR). Row mapping s = (jj*4+g)*64 + schunk:
// concurrent blocks read 256 consecutive rows. Partials -> d_out scratch.
// ---------------------------------------------------------------------------
__global__ __launch_bounds__(256, 8) void k_kvt(
    const float* __restrict__ v, const float* __restrict__ kh,
    float* __restrict__ part)
{
  const int schunk = blockIdx.x;   // 0..63
  const int dchunk = blockIdx.y;   // 0..7
  const int b = blockIdx.z;
  const int t = threadIdx.x;
  const int c = t & 31;
  const int hh2 = (t >> 5) & 1;
  const int g = t >> 6;            // 0..3
  const int d0 = dchunk*128 + c*4;
  float acc[8][4];
#pragma unroll
  for (int h = 0; h < 8; ++h) {
    acc[h][0] = 0.f; acc[h][1] = 0.f; acc[h][2] = 0.f; acc[h][3] = 0.f;
  }
#pragma unroll 2
  for (int jj = 0; jj < 16; ++jj) {
    const int s = (jj*4 + g)*64 + schunk;
    const size_t rb = (size_t)(b*SS + s);
    const float4 v4 = *(const float4*)(v + rb*DD + d0);
    const float4* khp = (const float4*)(kh + rb*HH) + hh2*2;
    const float4 k0 = khp[0], k1 = khp[1];
    const float kk[8] = {k0.x,k0.y,k0.z,k0.w, k1.x,k1.y,k1.z,k1.w};
#pragma unroll
    for (int h = 0; h < 8; ++h) {
      acc[h][0] = fmaf(kk[h], v4.x, acc[h][0]);
      acc[h][1] = fmaf(kk[h], v4.y, acc[h][1]);
      acc[h][2] = fmaf(kk[h], v4.z, acc[h][2]);
      acc[h][3] = fmaf(kk[h], v4.w, acc[h][3]);
    }
  }
  __shared__ float lds[4][2][128];
  const size_t pbase = (size_t)((b*8 + dchunk)*64 + schunk) * 2048;
#pragma unroll   // full unroll: acc indices stay compile-time
  for (int h = 0; h < 8; ++h) {
    *(float4*)&lds[g][hh2][c*4] =
        make_float4(acc[h][0], acc[h][1], acc[h][2], acc[h][3]);
    __syncthreads();
    {
      const int hh2r = t >> 7, dl = t & 127;
      const float sum = lds[0][hh2r][dl] + lds[1][hh2r][dl]
                      + lds[2][hh2r][dl] + lds[3][hh2r][dl];
      part[pbase + (hh2r*8 + h)*128 + dl] = sum;
    }
    __syncthreads();
  }
}

// ---------------------------------------------------------------------------
// K3: reduce part over the 64 schunks -> kvt[b][h][1024].
// Grid (8 dchunk, 4 b, 4 head-quarter), fully coalesced reads.
// ---------------------------------------------------------------------------
__global__ __launch_bounds__(256, 8) void k_red(
    const float* __restrict__ part, float* __restrict__ kvt)
{
  const int dchunk = blockIdx.x;
  const int b = blockIdx.y;
  const int hq = blockIdx.z;       // 0..3
  const int t = threadIdx.x;
  const size_t pb = (size_t)((b*8 + dchunk)*64) * 2048;
#pragma unroll
  for (int ho = 0; ho < 2; ++ho) {
    const int h = hq*4 + ho*2 + (t >> 7), dl = t & 127;
    float s = 0.f;
#pragma unroll 8
    for (int sc = 0; sc < 64; ++sc)
      s += part[pb + (size_t)sc*2048 + h*128 + dl];
    kvt[(size_t)(b*16 + h)*1024 + dchunk*128 + dl] = s;
  }
}

// ---------------------------------------------------------------------------
// K4: per (b,h): kv[b,h,dv] = sum_d kvt[b,h,d]*wv[d, h*64+dv] + ksum*bv,
// ksum = sum_s kh[b,s,h] computed in-block.
// ---------------------------------------------------------------------------
__global__ __launch_bounds__(256, 2) void k_kv(
    const float* __restrict__ kvt, const float* __restrict__ kh,
    const float* __restrict__ wv, const float* __restrict__ bv,
    float* __restrict__ kv)
{
  const int h = blockIdx.x;    // 0..15
  const int b = blockIdx.y;
  const int t = threadIdx.x;
  const int dg = t >> 6, c = t & 63;
  const float* kp = kvt + (size_t)(b*16 + h)*1024 + dg*256;
  const float* wp = wv + (size_t)(dg*256)*DD + h*64 + c;
  float p = 0.f;
#pragma unroll 4
  for (int dd = 0; dd < 256; ++dd)
    p = fmaf(kp[dd], wp[(size_t)dd*DD], p);
  float ks = 0.f;
#pragma unroll 4
  for (int m = 0; m < 16; ++m)
    ks += kh[(size_t)(b*SS + m*256 + t)*HH + h];
  __shared__ float red[256], redk[256];
  red[t] = p; redk[t] = ks;
  __syncthreads();
  if (t < 128) redk[t] += redk[t + 128];
  __syncthreads();
  if (t < 64) redk[t] += redk[t + 64];
  __syncthreads();
  if (t < 64) {
    float kst = redk[t];
#pragma unroll
    for (int off = 32; off > 0; off >>= 1) kst += __shfl_xor(kst, off);
    const float psum = red[t] + red[64+t] + red[128+t] + red[192+t];
    kv[(size_t)b*1024 + h*64 + t] = psum + kst * bv[h*64 + t];
  }
}

// ---------------------------------------------------------------------------
// K5: per (b,h): state = cumsum_h kv (HEAD-axis cumsum), then
// W2[b,h,d] = sum_dv state[dv] * wo[(h*64+dv), d]
// ---------------------------------------------------------------------------
__global__ __launch_bounds__(256) void k_w2(
    const float* __restrict__ kv, const float* __restrict__ wo,
    float* __restrict__ W2)
{
  const int bh = blockIdx.x;
  const int b = bh >> 4, h = bh & 15;
  const int t = threadIdx.x;
  __shared__ float st[64];
  if (t < 64) {
    float s = 0.f;
    for (int hp = 0; hp <= h; ++hp) s += kv[(size_t)b*1024 + hp*64 + t];
    st[t] = s;
  }
  __syncthreads();
  const int d0 = t * 4;
  float4 acc = {0.f, 0.f, 0.f, 0.f};
#pragma unroll 4
  for (int dv = 0; dv < 64; ++dv) {
    const float sv = st[dv];
    const float4 w4 = *(const float4*)(wo + (size_t)(h*64 + dv)*DD + d0);
    acc.x = fmaf(sv, w4.x, acc.x);
    acc.y = fmaf(sv, w4.y, acc.y);
    acc.z = fmaf(sv, w4.z, acc.z);
    acc.w = fmaf(sv, w4.w, acc.w);
  }
  *(float4*)(W2 + (size_t)(b*HH + h)*DD + d0) = acc;
}

// ---------------------------------------------------------------------------
// K6: out[b,s,:] = bo + sum_h qh[b,s,h] * W2[b,h,:]
// 2048 blocks x 8 rows; s = r*512 + bx -> 512 consecutive rows concurrent.
// Nontemporal stores.
// ---------------------------------------------------------------------------
__global__ __launch_bounds__(256, 4) void k_out(
    const float* __restrict__ qh, const float* __restrict__ W2,
    const float* __restrict__ bo, float* __restrict__ out)
{
  const int bx = blockIdx.x;   // 0..511
  const int b = blockIdx.y;
  const int t = threadIdx.x;
  const int d0 = t * 4;
  float4 w2[16];
#pragma unroll
  for (int h = 0; h < 16; ++h)
    w2[h] = *(const float4*)(W2 + (size_t)(b*HH + h)*DD + d0);
  const float4 bo4 = *(const float4*)(bo + d0);
  __shared__ float qs[128];
  if (t < 128)
    qs[t] = qh[(size_t)(b*SS + (t>>4)*512 + bx)*HH + (t & 15)];
  __syncthreads();
#pragma unroll
  for (int r = 0; r < 8; ++r) {
    const float4* qr = (const float4*)(qs + r*16);
    const float4 q0 = qr[0], q1 = qr[1], q2 = qr[2], q3 = qr[3];
    const float qv[16] = {q0.x,q0.y,q0.z,q0.w, q1.x,q1.y,q1.z,q1.w,
                          q2.x,q2.y,q2.z,q2.w, q3.x,q3.y,q3.z,q3.w};
    float4 o = bo4;
#pragma unroll
    for (int h = 0; h < 16; ++h) {
      o.x = fmaf(qv[h], w2[h].x, o.x);
      o.y = fmaf(qv[h], w2[h].y, o.y);
      o.z = fmaf(qv[h], w2[h].z, o.z);
      o.w = fmaf(qv[h], w2[h].w, o.w);
    }
    nfloat4 ov = { o.x, o.y, o.z, o.w };
    nfloat4* dst = (nfloat4*)(out + (size_t)(b*SS + r*512 + bx)*DD + d0);
    __builtin_nontemporal_store(ov, dst);
  }
}

// ---------------------------------------------------------------------------
extern "C" void kernel_launch(void* const* d_in, const int* in_sizes, int n_in,
                              void* d_out, int out_size, void* d_ws, size_t ws_size,
                              hipStream_t stream)
{
  const float* q  = (const float*)d_in[0];
  const float* k  = (const float*)d_in[1];
  const float* v  = (const float*)d_in[2];
  const float* wq = (const float*)d_in[3];
  const float* bq = (const float*)d_in[4];
  const float* wk = (const float*)d_in[5];
  const float* bk = (const float*)d_in[6];
  const float* wv = (const float*)d_in[7];
  const float* bv = (const float*)d_in[8];
  const float* wo = (const float*)d_in[9];
  const float* bo = (const float*)d_in[10];
  float* out = (float*)d_out;
  float* ws  = (float*)d_ws;

  // ws layout (floats): qh 262144 | kh 262144 | kvt 65536 | kv 4096 | W2 65536
  float* qh  = ws;
  float* kh  = ws + 262144;
  float* kvt = ws + 524288;
  float* kv  = ws + 589824;
  float* W2  = ws + 593920;
  // d_out scratch: kvT partials (2048 blocks * 2048 floats = 16 MB) at the
  // front; wf (weight fragments, 32K shorts = 64KB) right after. Both are
  // consumed before k_out fully overwrites d_out.
  float* part = out;
  short* wf   = (short*)(out + 4194304);

  hipLaunchKernelGGL(k_wfrag, dim3(2), dim3(256), 0, stream,
                     wq, wk, wf);
  hipLaunchKernelGGL(k_qhkh, dim3(512), dim3(256), 0, stream,
                     q, k, wf, bq, bk, qh, kh);
  hipLaunchKernelGGL(k_kvt, dim3(64, 8, 4), dim3(256), 0, stream,
                     v, kh, part);
  hipLaunchKernelGGL(k_red, dim3(8, 4, 4), dim3(256), 0, stream,
                     part, kvt);
  hipLaunchKernelGGL(k_kv, dim3(16, 4), dim3(256), 0, stream,
                     kvt, kh, wv, bv, kv);
  hipLaunchKernelGGL(k_w2, dim3(64), dim3(256), 0, stream,
                     kv, wo, W2);
  hipLaunchKernelGGL(k_out, dim3(512, 4), dim3(256), 0, stream,
                     qh, W2, bo, out);
}

// Round 7
// 107.374 us; speedup vs baseline: 2.8186x; 1.0078x over previous
//
#include <hip/hip_runtime.h>

#define SS 4096
#define DD 1024
#define HH 16

typedef float nfloat4 __attribute__((ext_vector_type(4)));
typedef __attribute__((ext_vector_type(8))) short bf16x8;
typedef __attribute__((ext_vector_type(4))) float f32x4;

__device__ __forceinline__ short f2bf(float f) {
  union { float f; unsigned u; } z; z.f = f;
  return (short)((z.u + 0x8000u) >> 16);    // round-half-up to bf16
}

// ---------------------------------------------------------------------------
// K0: pre-pack wq,wk into MFMA A-fragment order, bf16.
// wf[m][t][lane][e] = w_m[t*32 + (lane>>4)*8 + e][lane&15]
// ---------------------------------------------------------------------------
__global__ __launch_bounds__(256) void k_wfrag(
    const float* __restrict__ wq, const float* __restrict__ wk,
    short* __restrict__ wf)
{
  const int m = blockIdx.x;                 // 0=q, 1=k
  const float* __restrict__ w = m ? wk : wq;
  short* __restrict__ dst = wf + m * 16384;
  for (int p = threadIdx.x; p < 2048; p += 256) {   // p = t*64 + lane
    const int t = p >> 6, l = p & 63;
    const int kbase = t*32 + ((l >> 4) * 8), col = l & 15;
    short v[8];
#pragma unroll
    for (int e = 0; e < 8; ++e)
      v[e] = f2bf(w[(size_t)(kbase + e)*HH + col]);
    short* o = dst + (size_t)p * 8;
#pragma unroll
    for (int e = 0; e < 8; ++e) o[e] = v[e];
  }
}

// ---------------------------------------------------------------------------
// K1: qh/kh via MFMA 16x16x32 bf16, K SPLIT ACROSS THE 4 WAVES of a block.
// Block = one 16-row tile; wave w covers K in [w*256,(w+1)*256) = 8 MFMA
// steps; partial f32x4 accs combined via one LDS round. Grid = 2048 blocks
// -> 8192 waves = 100% wave-slot fill (vs 25% in round 6).
// ---------------------------------------------------------------------------
__global__ __launch_bounds__(256, 8) void k_qhkh(
    const float* __restrict__ q, const float* __restrict__ k,
    const short* __restrict__ wf,
    const float* __restrict__ bq, const float* __restrict__ bk,
    float* __restrict__ qh, float* __restrict__ kh)
{
  const int wid = threadIdx.x >> 6, lane = threadIdx.x & 63;
  const int tile = blockIdx.x;               // 0..2047
  const bool isk = tile >= 1024;
  const int t16 = isk ? (tile - 1024) : tile;
  const float* __restrict__ src = isk ? k : q;
  const short* __restrict__ wfm = wf + (isk ? 16384 : 0);
  const float* __restrict__ bias = isk ? bk : bq;
  float* __restrict__ dst = isk ? kh : qh;
  const int s0 = t16 * 16;                   // flat row over (B,S)
  const int row = lane & 15, g = lane >> 4;
  const float* __restrict__ xrow =
      src + (size_t)(s0 + row) * DD + wid*256 + g*8;
  const short* __restrict__ wfw = wfm + (size_t)(wid*8*64 + lane) * 8;
  f32x4 acc = {0.f, 0.f, 0.f, 0.f};
#pragma unroll
  for (int tt = 0; tt < 8; ++tt) {
    const bf16x8 a = *(const bf16x8*)(wfw + (size_t)(tt*64) * 8);
    const float4 x0 = *(const float4*)(xrow + tt*32);
    const float4 x1 = *(const float4*)(xrow + tt*32 + 4);
    bf16x8 bb;
    bb[0]=f2bf(x0.x); bb[1]=f2bf(x0.y); bb[2]=f2bf(x0.z); bb[3]=f2bf(x0.w);
    bb[4]=f2bf(x1.x); bb[5]=f2bf(x1.y); bb[6]=f2bf(x1.z); bb[7]=f2bf(x1.w);
    acc = __builtin_amdgcn_mfma_f32_16x16x32_bf16(a, bb, acc, 0, 0, 0);
  }
  __shared__ float lds[4][64][4];
  *(f32x4*)&lds[wid][lane][0] = acc;
  __syncthreads();
  // thread t -> output (row = t>>4, head = t&15); original acc lived at
  // lane' = (head>>2)*16 + row, reg j = head&3. Wave writes 4 rows = 256B
  // contiguous in dst.
  const int t = threadIdx.x;
  const int orow = t >> 4, ohead = t & 15;
  const int lane2 = ((ohead >> 2) << 4) + orow;
  const int j = ohead & 3;
  const float sacc = lds[0][lane2][j] + lds[1][lane2][j]
                   + lds[2][lane2][j] + lds[3][lane2][j];
  const float val = sacc + bias[ohead];
  dst[(size_t)(s0 + orow)*HH + ohead] = 1.f/(1.f + __expf(-val));
}

// ---------------------------------------------------------------------------
// K2: kvT partials.  Grid (64 schunk, 8 dchunk, 4 b) = 2048 blocks.
// Thread (c = t&31 -> 4 d's, hh2 = (t>>5)&1 -> head half, g = t>>6 -> row
// group). acc[8][4] (~32 VGPR). Row mapping s = (jj*4+g)*64 + schunk:
// concurrent blocks read 256 consecutive rows. Partials -> d_out scratch.
// ---------------------------------------------------------------------------
__global__ __launch_bounds__(256, 8) void k_kvt(
    const float* __restrict__ v, const float* __restrict__ kh,
    float* __restrict__ part)
{
  const int schunk = blockIdx.x;   // 0..63
  const int dchunk = blockIdx.y;   // 0..7
  const int b = blockIdx.z;
  const int t = threadIdx.x;
  const int c = t & 31;
  const int hh2 = (t >> 5) & 1;
  const int g = t >> 6;            // 0..3
  const int d0 = dchunk*128 + c*4;
  float acc[8][4];
#pragma unroll
  for (int h = 0; h < 8; ++h) {
    acc[h][0] = 0.f; acc[h][1] = 0.f; acc[h][2] = 0.f; acc[h][3] = 0.f;
  }
#pragma unroll 2
  for (int jj = 0; jj < 16; ++jj) {
    const int s = (jj*4 + g)*64 + schunk;
    const size_t rb = (size_t)(b*SS + s);
    const float4 v4 = *(const float4*)(v + rb*DD + d0);
    const float4* khp = (const float4*)(kh + rb*HH) + hh2*2;
    const float4 k0 = khp[0], k1 = khp[1];
    const float kk[8] = {k0.x,k0.y,k0.z,k0.w, k1.x,k1.y,k1.z,k1.w};
#pragma unroll
    for (int h = 0; h < 8; ++h) {
      acc[h][0] = fmaf(kk[h], v4.x, acc[h][0]);
      acc[h][1] = fmaf(kk[h], v4.y, acc[h][1]);
      acc[h][2] = fmaf(kk[h], v4.z, acc[h][2]);
      acc[h][3] = fmaf(kk[h], v4.w, acc[h][3]);
    }
  }
  __shared__ float lds[4][2][128];
  const size_t pbase = (size_t)((b*8 + dchunk)*64 + schunk) * 2048;
#pragma unroll   // full unroll: acc indices stay compile-time
  for (int h = 0; h < 8; ++h) {
    *(float4*)&lds[g][hh2][c*4] =
        make_float4(acc[h][0], acc[h][1], acc[h][2], acc[h][3]);
    __syncthreads();
    {
      const int hh2r = t >> 7, dl = t & 127;
      const float sum = lds[0][hh2r][dl] + lds[1][hh2r][dl]
                      + lds[2][hh2r][dl] + lds[3][hh2r][dl];
      part[pbase + (hh2r*8 + h)*128 + dl] = sum;
    }
    __syncthreads();
  }
}

// ---------------------------------------------------------------------------
// K3: reduce part over the 64 schunks -> kvt[b][h][1024].
// Grid (8 dchunk, 4 b, 4 head-quarter), fully coalesced reads.
// ---------------------------------------------------------------------------
__global__ __launch_bounds__(256, 8) void k_red(
    const float* __restrict__ part, float* __restrict__ kvt)
{
  const int dchunk = blockIdx.x;
  const int b = blockIdx.y;
  const int hq = blockIdx.z;       // 0..3
  const int t = threadIdx.x;
  const size_t pb = (size_t)((b*8 + dchunk)*64) * 2048;
#pragma unroll
  for (int ho = 0; ho < 2; ++ho) {
    const int h = hq*4 + ho*2 + (t >> 7), dl = t & 127;
    float s = 0.f;
#pragma unroll 8
    for (int sc = 0; sc < 64; ++sc)
      s += part[pb + (size_t)sc*2048 + h*128 + dl];
    kvt[(size_t)(b*16 + h)*1024 + dchunk*128 + dl] = s;
  }
}

// ---------------------------------------------------------------------------
// K4: per (b,h): kv[b,h,dv] = sum_d kvt[b,h,d]*wv[d, h*64+dv] + ksum*bv,
// ksum = sum_s kh[b,s,h] computed in-block.
// ---------------------------------------------------------------------------
__global__ __launch_bounds__(256, 2) void k_kv(
    const float* __restrict__ kvt, const float* __restrict__ kh,
    const float* __restrict__ wv, const float* __restrict__ bv,
    float* __restrict__ kv)
{
  const int h = blockIdx.x;    // 0..15
  const int b = blockIdx.y;
  const int t = threadIdx.x;
  const int dg = t >> 6, c = t & 63;
  const float* kp = kvt + (size_t)(b*16 + h)*1024 + dg*256;
  const float* wp = wv + (size_t)(dg*256)*DD + h*64 + c;
  float p = 0.f;
#pragma unroll 4
  for (int dd = 0; dd < 256; ++dd)
    p = fmaf(kp[dd], wp[(size_t)dd*DD], p);
  float ks = 0.f;
#pragma unroll 4
  for (int m = 0; m < 16; ++m)
    ks += kh[(size_t)(b*SS + m*256 + t)*HH + h];
  __shared__ float red[256], redk[256];
  red[t] = p; redk[t] = ks;
  __syncthreads();
  if (t < 128) redk[t] += redk[t + 128];
  __syncthreads();
  if (t < 64) redk[t] += redk[t + 64];
  __syncthreads();
  if (t < 64) {
    float kst = redk[t];
#pragma unroll
    for (int off = 32; off > 0; off >>= 1) kst += __shfl_xor(kst, off);
    const float psum = red[t] + red[64+t] + red[128+t] + red[192+t];
    kv[(size_t)b*1024 + h*64 + t] = psum + kst * bv[h*64 + t];
  }
}

// ---------------------------------------------------------------------------
// K5: per (b,h): state = cumsum_h kv (HEAD-axis cumsum), then
// W2[b,h,d] = sum_dv state[dv] * wo[(h*64+dv), d]
// ---------------------------------------------------------------------------
__global__ __launch_bounds__(256) void k_w2(
    const float* __restrict__ kv, const float* __restrict__ wo,
    float* __restrict__ W2)
{
  const int bh = blockIdx.x;
  const int b = bh >> 4, h = bh & 15;
  const int t = threadIdx.x;
  __shared__ float st[64];
  if (t < 64) {
    float s = 0.f;
    for (int hp = 0; hp <= h; ++hp) s += kv[(size_t)b*1024 + hp*64 + t];
    st[t] = s;
  }
  __syncthreads();
  const int d0 = t * 4;
  float4 acc = {0.f, 0.f, 0.f, 0.f};
#pragma unroll 4
  for (int dv = 0; dv < 64; ++dv) {
    const float sv = st[dv];
    const float4 w4 = *(const float4*)(wo + (size_t)(h*64 + dv)*DD + d0);
    acc.x = fmaf(sv, w4.x, acc.x);
    acc.y = fmaf(sv, w4.y, acc.y);
    acc.z = fmaf(sv, w4.z, acc.z);
    acc.w = fmaf(sv, w4.w, acc.w);
  }
  *(float4*)(W2 + (size_t)(b*HH + h)*DD + d0) = acc;
}

// ---------------------------------------------------------------------------
// K6: out[b,s,:] = bo + sum_h qh[b,s,h] * W2[b,h,:]
// 2048 blocks x 8 rows; s = r*512 + bx -> 512 consecutive rows concurrent.
// Nontemporal stores.
// ---------------------------------------------------------------------------
__global__ __launch_bounds__(256, 4) void k_out(
    const float* __restrict__ qh, const float* __restrict__ W2,
    const float* __restrict__ bo, float* __restrict__ out)
{
  const int bx = blockIdx.x;   // 0..511
  const int b = blockIdx.y;
  const int t = threadIdx.x;
  const int d0 = t * 4;
  float4 w2[16];
#pragma unroll
  for (int h = 0; h < 16; ++h)
    w2[h] = *(const float4*)(W2 + (size_t)(b*HH + h)*DD + d0);
  const float4 bo4 = *(const float4*)(bo + d0);
  __shared__ float qs[128];
  if (t < 128)
    qs[t] = qh[(size_t)(b*SS + (t>>4)*512 + bx)*HH + (t & 15)];
  __syncthreads();
#pragma unroll
  for (int r = 0; r < 8; ++r) {
    const float4* qr = (const float4*)(qs + r*16);
    const float4 q0 = qr[0], q1 = qr[1], q2 = qr[2], q3 = qr[3];
    const float qv[16] = {q0.x,q0.y,q0.z,q0.w, q1.x,q1.y,q1.z,q1.w,
                          q2.x,q2.y,q2.z,q2.w, q3.x,q3.y,q3.z,q3.w};
    float4 o = bo4;
#pragma unroll
    for (int h = 0; h < 16; ++h) {
      o.x = fmaf(qv[h], w2[h].x, o.x);
      o.y = fmaf(qv[h], w2[h].y, o.y);
      o.z = fmaf(qv[h], w2[h].z, o.z);
      o.w = fmaf(qv[h], w2[h].w, o.w);
    }
    nfloat4 ov = { o.x, o.y, o.z, o.w };
    nfloat4* dst = (nfloat4*)(out + (size_t)(b*SS + r*512 + bx)*DD + d0);
    __builtin_nontemporal_store(ov, dst);
  }
}

// ---------------------------------------------------------------------------
extern "C" void kernel_launch(void* const* d_in, const int* in_sizes, int n_in,
                              void* d_out, int out_size, void* d_ws, size_t ws_size,
                              hipStream_t stream)
{
  const float* q  = (const float*)d_in[0];
  const float* k  = (const float*)d_in[1];
  const float* v  = (const float*)d_in[2];
  const float* wq = (const float*)d_in[3];
  const float* bq = (const float*)d_in[4];
  const float* wk = (const float*)d_in[5];
  const float* bk = (const float*)d_in[6];
  const float* wv = (const float*)d_in[7];
  const float* bv = (const float*)d_in[8];
  const float* wo = (const float*)d_in[9];
  const float* bo = (const float*)d_in[10];
  float* out = (float*)d_out;
  float* ws  = (float*)d_ws;

  // ws layout (floats): qh 262144 | kh 262144 | kvt 65536 | kv 4096 | W2 65536
  float* qh  = ws;
  float* kh  = ws + 262144;
  float* kvt = ws + 524288;
  float* kv  = ws + 589824;
  float* W2  = ws + 593920;
  // d_out scratch: kvT partials (2048 blocks * 2048 floats = 16 MB) at the
  // front; wf (weight fragments, 32K shorts = 64KB) right after. Both are
  // consumed before k_out fully overwrites d_out.
  float* part = out;
  short* wf   = (short*)(out + 4194304);

  hipLaunchKernelGGL(k_wfrag, dim3(2), dim3(256), 0, stream,
                     wq, wk, wf);
  hipLaunchKernelGGL(k_qhkh, dim3(2048), dim3(256), 0, stream,
                     q, k, wf, bq, bk, qh, kh);
  hipLaunchKernelGGL(k_kvt, dim3(64, 8, 4), dim3(256), 0, stream,
                     v, kh, part);
  hipLaunchKernelGGL(k_red, dim3(8, 4, 4), dim3(256), 0, stream,
                     part, kvt);
  hipLaunchKernelGGL(k_kv, dim3(16, 4), dim3(256), 0, stream,
                     kvt, kh, wv, bv, kv);
  hipLaunchKernelGGL(k_w2, dim3(64), dim3(256), 0, stream,
                     kv, wo, W2);
  hipLaunchKernelGGL(k_out, dim3(512, 4), dim3(256), 0, stream,
                     qh, W2, bo, out);
}

// Round 8
// 106.657 us; speedup vs baseline: 2.8375x; 1.0067x over previous
//
#include <hip/hip_runtime.h>

#define SS 4096
#define DD 1024
#define HH 16

typedef float nfloat4 __attribute__((ext_vector_type(4)));
typedef __attribute__((ext_vector_type(8))) short bf16x8;
typedef __attribute__((ext_vector_type(4))) float f32x4;

__device__ __forceinline__ short f2bf(float f) {
  union { float f; unsigned u; } z; z.f = f;
  return (short)((z.u + 0x8000u) >> 16);    // round-half-up to bf16
}

// ---------------------------------------------------------------------------
// K0: pre-pack wq,wk into MFMA A-fragment order, bf16.
// wf[m][t][lane][e] = w_m[t*32 + (lane>>4)*8 + e][lane&15]
// ---------------------------------------------------------------------------
__global__ __launch_bounds__(256) void k_wfrag(
    const float* __restrict__ wq, const float* __restrict__ wk,
    short* __restrict__ wf)
{
  const int m = blockIdx.x;                 // 0=q, 1=k
  const float* __restrict__ w = m ? wk : wq;
  short* __restrict__ dst = wf + m * 16384;
  for (int p = threadIdx.x; p < 2048; p += 256) {   // p = t*64 + lane
    const int t = p >> 6, l = p & 63;
    const int kbase = t*32 + ((l >> 4) * 8), col = l & 15;
    short v[8];
#pragma unroll
    for (int e = 0; e < 8; ++e)
      v[e] = f2bf(w[(size_t)(kbase + e)*HH + col]);
    short* o = dst + (size_t)p * 8;
#pragma unroll
    for (int e = 0; e < 8; ++e) o[e] = v[e];
  }
}

// ---------------------------------------------------------------------------
// K1: qh/kh via MFMA 16x16x32 bf16. Block = one 16-row tile, K split across
// the 4 waves. ALL global loads coalesced: the 16x1024 fp32 tile is staged
// into LDS as bf16 via 16 x 1KB-per-wave float4 loads (row-scatter paid in
// LDS, not in the TA). XOR swizzle colByte ^= (row&7)<<4 makes the strided
// ds_read_b128 fragment reads hit the structural 8-access/bank minimum.
// ---------------------------------------------------------------------------
__global__ __launch_bounds__(256, 4) void k_qhkh(
    const float* __restrict__ q, const float* __restrict__ k,
    const short* __restrict__ wf,
    const float* __restrict__ bq, const float* __restrict__ bk,
    float* __restrict__ qh, float* __restrict__ kh)
{
  const int t = threadIdx.x;
  const int wid = t >> 6, lane = t & 63;
  const int tile = blockIdx.x;               // 0..2047
  const bool isk = tile >= 1024;
  const int t16 = isk ? (tile - 1024) : tile;
  const float* __restrict__ src = isk ? k : q;
  const short* __restrict__ wfm = wf + (isk ? 16384 : 0);
  const float* __restrict__ bias = isk ? bk : bq;
  float* __restrict__ dst = isk ? kh : qh;
  const int s0 = t16 * 16;                   // flat row over (B,S)

  __shared__ short xs[16 * 1024];            // 32 KB, swizzled bf16 tile

  // A-fragments for this wave's K-quarter: preload into registers (L2-hot,
  // coalesced 1KB/wave loads, independent of staging).
  const short* __restrict__ wfw = wfm + (size_t)(wid*8*64 + lane) * 8;
  bf16x8 afrag[8];
#pragma unroll
  for (int tt = 0; tt < 8; ++tt)
    afrag[tt] = *(const bf16x8*)(wfw + (size_t)(tt*64) * 8);

  // Stage: thread t covers row rr, cols [4t, 4t+4). Per wave-instr: 1KB
  // contiguous global read. Convert fp32->bf16, swizzled 8B LDS write.
  {
    const float* __restrict__ srow = src + (size_t)s0 * DD + t*4;
#pragma unroll 4
    for (int rr = 0; rr < 16; ++rr) {
      const float4 x4 = *(const float4*)(srow + (size_t)rr * DD);
      short4 b4;
      b4.x = f2bf(x4.x); b4.y = f2bf(x4.y);
      b4.z = f2bf(x4.z); b4.w = f2bf(x4.w);
      const int colb = (t*8) ^ ((rr & 7) << 4);
      *(short4*)((char*)xs + rr*2048 + colb) = b4;
    }
  }
  __syncthreads();

  // MFMA: wave wid covers K in [wid*256,(wid+1)*256) = 8 steps.
  const int row = lane & 15, g = lane >> 4;
  const char* __restrict__ xrow = (const char*)xs + row*2048;
  f32x4 acc = {0.f, 0.f, 0.f, 0.f};
#pragma unroll
  for (int tt = 0; tt < 8; ++tt) {
    const int colb = ((wid*256 + tt*32 + g*8) * 2) ^ ((row & 7) << 4);
    const bf16x8 bb = *(const bf16x8*)(xrow + colb);
    acc = __builtin_amdgcn_mfma_f32_16x16x32_bf16(afrag[tt], bb, acc, 0, 0, 0);
  }

  // Combine the 4 K-partials via LDS (reuse xs), then sigmoid + store.
  __syncthreads();
  float* red = (float*)xs;                   // [4][64][4]
  *(f32x4*)&red[(wid*64 + lane)*4] = acc;
  __syncthreads();
  const int orow = t >> 4, ohead = t & 15;
  const int lane2 = ((ohead >> 2) << 4) + orow;
  const int j = ohead & 3;
  const float sacc = red[0*256 + lane2*4 + j] + red[1*256 + lane2*4 + j]
                   + red[2*256 + lane2*4 + j] + red[3*256 + lane2*4 + j];
  const float val = sacc + bias[ohead];
  dst[(size_t)(s0 + orow)*HH + ohead] = 1.f/(1.f + __expf(-val));
}

// ---------------------------------------------------------------------------
// K2: kvT partials.  Grid (64 schunk, 8 dchunk, 4 b) = 2048 blocks.
// Thread (c = t&31 -> 4 d's, hh2 = (t>>5)&1 -> head half, g = t>>6 -> row
// group). acc[8][4] (~32 VGPR). Row mapping s = (jj*4+g)*64 + schunk:
// concurrent blocks read 256 consecutive rows. Partials -> d_out scratch.
// ---------------------------------------------------------------------------
__global__ __launch_bounds__(256, 8) void k_kvt(
    const float* __restrict__ v, const float* __restrict__ kh,
    float* __restrict__ part)
{
  const int schunk = blockIdx.x;   // 0..63
  const int dchunk = blockIdx.y;   // 0..7
  const int b = blockIdx.z;
  const int t = threadIdx.x;
  const int c = t & 31;
  const int hh2 = (t >> 5) & 1;
  const int g = t >> 6;            // 0..3
  const int d0 = dchunk*128 + c*4;
  float acc[8][4];
#pragma unroll
  for (int h = 0; h < 8; ++h) {
    acc[h][0] = 0.f; acc[h][1] = 0.f; acc[h][2] = 0.f; acc[h][3] = 0.f;
  }
#pragma unroll 2
  for (int jj = 0; jj < 16; ++jj) {
    const int s = (jj*4 + g)*64 + schunk;
    const size_t rb = (size_t)(b*SS + s);
    const float4 v4 = *(const float4*)(v + rb*DD + d0);
    const float4* khp = (const float4*)(kh + rb*HH) + hh2*2;
    const float4 k0 = khp[0], k1 = khp[1];
    const float kk[8] = {k0.x,k0.y,k0.z,k0.w, k1.x,k1.y,k1.z,k1.w};
#pragma unroll
    for (int h = 0; h < 8; ++h) {
      acc[h][0] = fmaf(kk[h], v4.x, acc[h][0]);
      acc[h][1] = fmaf(kk[h], v4.y, acc[h][1]);
      acc[h][2] = fmaf(kk[h], v4.z, acc[h][2]);
      acc[h][3] = fmaf(kk[h], v4.w, acc[h][3]);
    }
  }
  __shared__ float lds[4][2][128];
  const size_t pbase = (size_t)((b*8 + dchunk)*64 + schunk) * 2048;
#pragma unroll   // full unroll: acc indices stay compile-time
  for (int h = 0; h < 8; ++h) {
    *(float4*)&lds[g][hh2][c*4] =
        make_float4(acc[h][0], acc[h][1], acc[h][2], acc[h][3]);
    __syncthreads();
    {
      const int hh2r = t >> 7, dl = t & 127;
      const float sum = lds[0][hh2r][dl] + lds[1][hh2r][dl]
                      + lds[2][hh2r][dl] + lds[3][hh2r][dl];
      part[pbase + (hh2r*8 + h)*128 + dl] = sum;
    }
    __syncthreads();
  }
}

// ---------------------------------------------------------------------------
// K3: reduce part over the 64 schunks -> kvt[b][h][1024].
// Grid (8 dchunk, 4 b, 4 head-quarter), fully coalesced reads.
// ---------------------------------------------------------------------------
__global__ __launch_bounds__(256, 8) void k_red(
    const float* __restrict__ part, float* __restrict__ kvt)
{
  const int dchunk = blockIdx.x;
  const int b = blockIdx.y;
  const int hq = blockIdx.z;       // 0..3
  const int t = threadIdx.x;
  const size_t pb = (size_t)((b*8 + dchunk)*64) * 2048;
#pragma unroll
  for (int ho = 0; ho < 2; ++ho) {
    const int h = hq*4 + ho*2 + (t >> 7), dl = t & 127;
    float s = 0.f;
#pragma unroll 8
    for (int sc = 0; sc < 64; ++sc)
      s += part[pb + (size_t)sc*2048 + h*128 + dl];
    kvt[(size_t)(b*16 + h)*1024 + dchunk*128 + dl] = s;
  }
}

// ---------------------------------------------------------------------------
// K4: per (b,h): kv[b,h,dv] = sum_d kvt[b,h,d]*wv[d, h*64+dv] + ksum*bv,
// ksum = sum_s kh[b,s,h] computed in-block.
// ---------------------------------------------------------------------------
__global__ __launch_bounds__(256, 2) void k_kv(
    const float* __restrict__ kvt, const float* __restrict__ kh,
    const float* __restrict__ wv, const float* __restrict__ bv,
    float* __restrict__ kv)
{
  const int h = blockIdx.x;    // 0..15
  const int b = blockIdx.y;
  const int t = threadIdx.x;
  const int dg = t >> 6, c = t & 63;
  const float* kp = kvt + (size_t)(b*16 + h)*1024 + dg*256;
  const float* wp = wv + (size_t)(dg*256)*DD + h*64 + c;
  float p = 0.f;
#pragma unroll 4
  for (int dd = 0; dd < 256; ++dd)
    p = fmaf(kp[dd], wp[(size_t)dd*DD], p);
  float ks = 0.f;
#pragma unroll 4
  for (int m = 0; m < 16; ++m)
    ks += kh[(size_t)(b*SS + m*256 + t)*HH + h];
  __shared__ float red[256], redk[256];
  red[t] = p; redk[t] = ks;
  __syncthreads();
  if (t < 128) redk[t] += redk[t + 128];
  __syncthreads();
  if (t < 64) redk[t] += redk[t + 64];
  __syncthreads();
  if (t < 64) {
    float kst = redk[t];
#pragma unroll
    for (int off = 32; off > 0; off >>= 1) kst += __shfl_xor(kst, off);
    const float psum = red[t] + red[64+t] + red[128+t] + red[192+t];
    kv[(size_t)b*1024 + h*64 + t] = psum + kst * bv[h*64 + t];
  }
}

// ---------------------------------------------------------------------------
// K5: per (b,h): state = cumsum_h kv (HEAD-axis cumsum), then
// W2[b,h,d] = sum_dv state[dv] * wo[(h*64+dv), d]
// ---------------------------------------------------------------------------
__global__ __launch_bounds__(256) void k_w2(
    const float* __restrict__ kv, const float* __restrict__ wo,
    float* __restrict__ W2)
{
  const int bh = blockIdx.x;
  const int b = bh >> 4, h = bh & 15;
  const int t = threadIdx.x;
  __shared__ float st[64];
  if (t < 64) {
    float s = 0.f;
    for (int hp = 0; hp <= h; ++hp) s += kv[(size_t)b*1024 + hp*64 + t];
    st[t] = s;
  }
  __syncthreads();
  const int d0 = t * 4;
  float4 acc = {0.f, 0.f, 0.f, 0.f};
#pragma unroll 4
  for (int dv = 0; dv < 64; ++dv) {
    const float sv = st[dv];
    const float4 w4 = *(const float4*)(wo + (size_t)(h*64 + dv)*DD + d0);
    acc.x = fmaf(sv, w4.x, acc.x);
    acc.y = fmaf(sv, w4.y, acc.y);
    acc.z = fmaf(sv, w4.z, acc.z);
    acc.w = fmaf(sv, w4.w, acc.w);
  }
  *(float4*)(W2 + (size_t)(b*HH + h)*DD + d0) = acc;
}

// ---------------------------------------------------------------------------
// K6: out[b,s,:] = bo + sum_h qh[b,s,h] * W2[b,h,:]
// 2048 blocks x 8 rows; s = r*512 + bx -> 512 consecutive rows concurrent.
// Nontemporal stores.
// ---------------------------------------------------------------------------
__global__ __launch_bounds__(256, 4) void k_out(
    const float* __restrict__ qh, const float* __restrict__ W2,
    const float* __restrict__ bo, float* __restrict__ out)
{
  const int bx = blockIdx.x;   // 0..511
  const int b = blockIdx.y;
  const int t = threadIdx.x;
  const int d0 = t * 4;
  float4 w2[16];
#pragma unroll
  for (int h = 0; h < 16; ++h)
    w2[h] = *(const float4*)(W2 + (size_t)(b*HH + h)*DD + d0);
  const float4 bo4 = *(const float4*)(bo + d0);
  __shared__ float qs[128];
  if (t < 128)
    qs[t] = qh[(size_t)(b*SS + (t>>4)*512 + bx)*HH + (t & 15)];
  __syncthreads();
#pragma unroll
  for (int r = 0; r < 8; ++r) {
    const float4* qr = (const float4*)(qs + r*16);
    const float4 q0 = qr[0], q1 = qr[1], q2 = qr[2], q3 = qr[3];
    const float qv[16] = {q0.x,q0.y,q0.z,q0.w, q1.x,q1.y,q1.z,q1.w,
                          q2.x,q2.y,q2.z,q2.w, q3.x,q3.y,q3.z,q3.w};
    float4 o = bo4;
#pragma unroll
    for (int h = 0; h < 16; ++h) {
      o.x = fmaf(qv[h], w2[h].x, o.x);
      o.y = fmaf(qv[h], w2[h].y, o.y);
      o.z = fmaf(qv[h], w2[h].z, o.z);
      o.w = fmaf(qv[h], w2[h].w, o.w);
    }
    nfloat4 ov = { o.x, o.y, o.z, o.w };
    nfloat4* dst = (nfloat4*)(out + (size_t)(b*SS + r*512 + bx)*DD + d0);
    __builtin_nontemporal_store(ov, dst);
  }
}

// ---------------------------------------------------------------------------
extern "C" void kernel_launch(void* const* d_in, const int* in_sizes, int n_in,
                              void* d_out, int out_size, void* d_ws, size_t ws_size,
                              hipStream_t stream)
{
  const float* q  = (const float*)d_in[0];
  const float* k  = (const float*)d_in[1];
  const float* v  = (const float*)d_in[2];
  const float* wq = (const float*)d_in[3];
  const float* bq = (const float*)d_in[4];
  const float* wk = (const float*)d_in[5];
  const float* bk = (const float*)d_in[6];
  const float* wv = (const float*)d_in[7];
  const float* bv = (const float*)d_in[8];
  const float* wo = (const float*)d_in[9];
  const float* bo = (const float*)d_in[10];
  float* out = (float*)d_out;
  float* ws  = (float*)d_ws;

  // ws layout (floats): qh 262144 | kh 262144 | kvt 65536 | kv 4096 | W2 65536
  float* qh  = ws;
  float* kh  = ws + 262144;
  float* kvt = ws + 524288;
  float* kv  = ws + 589824;
  float* W2  = ws + 593920;
  // d_out scratch: kvT partials (2048 blocks * 2048 floats = 16 MB) at the
  // front; wf (weight fragments, 32K shorts = 64KB) right after. Both are
  // consumed before k_out fully overwrites d_out.
  float* part = out;
  short* wf   = (short*)(out + 4194304);

  hipLaunchKernelGGL(k_wfrag, dim3(2), dim3(256), 0, stream,
                     wq, wk, wf);
  hipLaunchKernelGGL(k_qhkh, dim3(2048), dim3(256), 0, stream,
                     q, k, wf, bq, bk, qh, kh);
  hipLaunchKernelGGL(k_kvt, dim3(64, 8, 4), dim3(256), 0, stream,
                     v, kh, part);
  hipLaunchKernelGGL(k_red, dim3(8, 4, 4), dim3(256), 0, stream,
                     part, kvt);
  hipLaunchKernelGGL(k_kv, dim3(16, 4), dim3(256), 0, stream,
                     kvt, kh, wv, bv, kv);
  hipLaunchKernelGGL(k_w2, dim3(64), dim3(256), 0, stream,
                     kv, wo, W2);
  hipLaunchKernelGGL(k_out, dim3(512, 4), dim3(256), 0, stream,
                     qh, W2, bo, out);
}

// Round 9
// 104.321 us; speedup vs baseline: 2.9011x; 1.0224x over previous
//
#include <hip/hip_runtime.h>

#define SS 4096
#define DD 1024
#define HH 16

typedef float nfloat4 __attribute__((ext_vector_type(4)));
typedef __attribute__((ext_vector_type(8))) short bf16x8;
typedef __attribute__((ext_vector_type(4))) float f32x4;

__device__ __forceinline__ short f2bf(float f) {
  union { float f; unsigned u; } z; z.f = f;
  return (short)((z.u + 0x8000u) >> 16);    // round-half-up to bf16
}

// ---------------------------------------------------------------------------
// K0: pre-pack wq,wk into MFMA A-fragment order, bf16.
// wf[m][t][lane][e] = w_m[t*32 + (lane>>4)*8 + e][lane&15]
// ---------------------------------------------------------------------------
__global__ __launch_bounds__(256) void k_wfrag(
    const float* __restrict__ wq, const float* __restrict__ wk,
    short* __restrict__ wf)
{
  const int m = blockIdx.x;                 // 0=q, 1=k
  const float* __restrict__ w = m ? wk : wq;
  short* __restrict__ dst = wf + m * 16384;
  for (int p = threadIdx.x; p < 2048; p += 256) {   // p = t*64 + lane
    const int t = p >> 6, l = p & 63;
    const int kbase = t*32 + ((l >> 4) * 8), col = l & 15;
    short v[8];
#pragma unroll
    for (int e = 0; e < 8; ++e)
      v[e] = f2bf(w[(size_t)(kbase + e)*HH + col]);
    short* o = dst + (size_t)p * 8;
#pragma unroll
    for (int e = 0; e < 8; ++e) o[e] = v[e];
  }
}

// ---------------------------------------------------------------------------
// K1: qh/kh via MFMA 16x16x32 bf16, SOFTWARE-PIPELINED over 2 tiles/block.
// 1024 blocks: 0..511 -> q tiles, 512..1023 -> k tiles; block handles tiles
// tbase, tbase+1. Per iteration: convert staged regs -> swizzled LDS, then
// ISSUE the next tile's 16 independent 1KB-coalesced loads (in flight across
// the MFMA+reduce phase -> ~256KB/CU outstanding), barrier, MFMA (K split
// across 4 waves), LDS-reduce partials, sigmoid, store.
// ---------------------------------------------------------------------------
__global__ __launch_bounds__(256, 4) void k_qhkh(
    const float* __restrict__ q, const float* __restrict__ k,
    const short* __restrict__ wf,
    const float* __restrict__ bq, const float* __restrict__ bk,
    float* __restrict__ qh, float* __restrict__ kh)
{
  const int t = threadIdx.x;
  const int wid = t >> 6, lane = t & 63;
  const bool isk = blockIdx.x >= 512;
  const int tbase = (blockIdx.x & 511) * 2;
  const float* __restrict__ src = isk ? k : q;
  const short* __restrict__ wfm = wf + (isk ? 16384 : 0);
  const float* __restrict__ bias = isk ? bk : bq;
  float* __restrict__ dst = isk ? kh : qh;

  __shared__ short xs[16 * 1024];            // 32 KB swizzled bf16 tile
  __shared__ float red[4 * 64 * 4];          // 4 KB partial-acc reduce

  // prologue: issue tile-0 stage loads FIRST (longest latency)
  float4 f[16];
  {
    const float* __restrict__ srow = src + (size_t)(tbase*16) * DD + t*4;
#pragma unroll
    for (int rr = 0; rr < 16; ++rr)
      f[rr] = *(const float4*)(srow + (size_t)rr * DD);
  }
  // A-fragments (L2-hot, coalesced)
  const short* __restrict__ wfw = wfm + (size_t)(wid*8*64 + lane) * 8;
  bf16x8 afrag[8];
#pragma unroll
  for (int tt = 0; tt < 8; ++tt)
    afrag[tt] = *(const bf16x8*)(wfw + (size_t)(tt*64) * 8);

  const int row = lane & 15, g = lane >> 4;
  const int orow = t >> 4, ohead = t & 15;
  const int lane2 = ((ohead >> 2) << 4) + orow;
  const int j = ohead & 3;
  const float mybias = bias[ohead];

#pragma unroll
  for (int i = 0; i < 2; ++i) {
    const int s0 = (tbase + i) * 16;
    // convert staged regs -> swizzled LDS (compiler waits vmcnt here)
#pragma unroll
    for (int rr = 0; rr < 16; ++rr) {
      short4 b4;
      b4.x = f2bf(f[rr].x); b4.y = f2bf(f[rr].y);
      b4.z = f2bf(f[rr].z); b4.w = f2bf(f[rr].w);
      const int colb = (t*8) ^ ((rr & 7) << 4);
      *(short4*)((char*)xs + rr*2048 + colb) = b4;
    }
    // issue NEXT tile's loads: in flight across MFMA + reduce below
    if (i == 0) {
      const float* __restrict__ srow =
          src + (size_t)((tbase + 1)*16) * DD + t*4;
#pragma unroll
      for (int rr = 0; rr < 16; ++rr)
        f[rr] = *(const float4*)(srow + (size_t)rr * DD);
    }
    __syncthreads();                         // xs ready (also: prev red reads done)

    // MFMA: wave wid covers K in [wid*256,(wid+1)*256) = 8 steps
    const char* __restrict__ xrow = (const char*)xs + row*2048;
    f32x4 acc = {0.f, 0.f, 0.f, 0.f};
#pragma unroll
    for (int tt = 0; tt < 8; ++tt) {
      const int colb = ((wid*256 + tt*32 + g*8) * 2) ^ ((row & 7) << 4);
      const bf16x8 bb = *(const bf16x8*)(xrow + colb);
      acc = __builtin_amdgcn_mfma_f32_16x16x32_bf16(afrag[tt], bb, acc, 0, 0, 0);
    }
    *(f32x4*)&red[(wid*64 + lane)*4] = acc;
    __syncthreads();                         // red ready (also: xs reads done)
    const float sacc = red[0*256 + lane2*4 + j] + red[1*256 + lane2*4 + j]
                     + red[2*256 + lane2*4 + j] + red[3*256 + lane2*4 + j];
    const float val = sacc + mybias;
    dst[(size_t)(s0 + orow)*HH + ohead] = 1.f/(1.f + __expf(-val));
  }
}

// ---------------------------------------------------------------------------
// K2: kvT partials.  Grid (32 schunk, 8 dchunk, 4 b) = 1024 blocks, 128
// rows/block (part halved to 8MB vs R8). Thread (c = t&31 -> 4 d's,
// hh2 = (t>>5)&1 -> head half, g = t>>6 -> row group). Row mapping
// s = (jj*4+g)*32 + schunk: concurrent blocks read consecutive rows.
// ---------------------------------------------------------------------------
__global__ __launch_bounds__(256, 8) void k_kvt(
    const float* __restrict__ v, const float* __restrict__ kh,
    float* __restrict__ part)
{
  const int schunk = blockIdx.x;   // 0..31
  const int dchunk = blockIdx.y;   // 0..7
  const int b = blockIdx.z;
  const int t = threadIdx.x;
  const int c = t & 31;
  const int hh2 = (t >> 5) & 1;
  const int g = t >> 6;            // 0..3
  const int d0 = dchunk*128 + c*4;
  float acc[8][4];
#pragma unroll
  for (int h = 0; h < 8; ++h) {
    acc[h][0] = 0.f; acc[h][1] = 0.f; acc[h][2] = 0.f; acc[h][3] = 0.f;
  }
#pragma unroll 2
  for (int jj = 0; jj < 32; ++jj) {
    const int s = (jj*4 + g)*32 + schunk;
    const size_t rb = (size_t)(b*SS + s);
    const float4 v4 = *(const float4*)(v + rb*DD + d0);
    const float4* khp = (const float4*)(kh + rb*HH) + hh2*2;
    const float4 k0 = khp[0], k1 = khp[1];
    const float kk[8] = {k0.x,k0.y,k0.z,k0.w, k1.x,k1.y,k1.z,k1.w};
#pragma unroll
    for (int h = 0; h < 8; ++h) {
      acc[h][0] = fmaf(kk[h], v4.x, acc[h][0]);
      acc[h][1] = fmaf(kk[h], v4.y, acc[h][1]);
      acc[h][2] = fmaf(kk[h], v4.z, acc[h][2]);
      acc[h][3] = fmaf(kk[h], v4.w, acc[h][3]);
    }
  }
  __shared__ float lds[4][2][128];
  const size_t pbase = (size_t)((b*8 + dchunk)*32 + schunk) * 2048;
#pragma unroll   // full unroll: acc indices stay compile-time
  for (int h = 0; h < 8; ++h) {
    *(float4*)&lds[g][hh2][c*4] =
        make_float4(acc[h][0], acc[h][1], acc[h][2], acc[h][3]);
    __syncthreads();
    {
      const int hh2r = t >> 7, dl = t & 127;
      const float sum = lds[0][hh2r][dl] + lds[1][hh2r][dl]
                      + lds[2][hh2r][dl] + lds[3][hh2r][dl];
      part[pbase + (hh2r*8 + h)*128 + dl] = sum;
    }
    __syncthreads();
  }
}

// ---------------------------------------------------------------------------
// K3: reduce part over the 32 schunks -> kvt[b][h][1024].
// Grid (8 dchunk, 4 b, 4 head-quarter), fully coalesced reads.
// ---------------------------------------------------------------------------
__global__ __launch_bounds__(256, 8) void k_red(
    const float* __restrict__ part, float* __restrict__ kvt)
{
  const int dchunk = blockIdx.x;
  const int b = blockIdx.y;
  const int hq = blockIdx.z;       // 0..3
  const int t = threadIdx.x;
  const size_t pb = (size_t)((b*8 + dchunk)*32) * 2048;
#pragma unroll
  for (int ho = 0; ho < 2; ++ho) {
    const int h = hq*4 + ho*2 + (t >> 7), dl = t & 127;
    float s = 0.f;
#pragma unroll 8
    for (int sc = 0; sc < 32; ++sc)
      s += part[pb + (size_t)sc*2048 + h*128 + dl];
    kvt[(size_t)(b*16 + h)*1024 + dchunk*128 + dl] = s;
  }
}

// ---------------------------------------------------------------------------
// K4: per (b,h): kv[b,h,dv] = sum_d kvt[b,h,d]*wv[d, h*64+dv] + ksum*bv,
// ksum = sum_s kh[b,s,h] computed in-block.
// ---------------------------------------------------------------------------
__global__ __launch_bounds__(256, 2) void k_kv(
    const float* __restrict__ kvt, const float* __restrict__ kh,
    const float* __restrict__ wv, const float* __restrict__ bv,
    float* __restrict__ kv)
{
  const int h = blockIdx.x;    // 0..15
  const int b = blockIdx.y;
  const int t = threadIdx.x;
  const int dg = t >> 6, c = t & 63;
  const float* kp = kvt + (size_t)(b*16 + h)*1024 + dg*256;
  const float* wp = wv + (size_t)(dg*256)*DD + h*64 + c;
  float p = 0.f;
#pragma unroll 4
  for (int dd = 0; dd < 256; ++dd)
    p = fmaf(kp[dd], wp[(size_t)dd*DD], p);
  float ks = 0.f;
#pragma unroll 4
  for (int m = 0; m < 16; ++m)
    ks += kh[(size_t)(b*SS + m*256 + t)*HH + h];
  __shared__ float red[256], redk[256];
  red[t] = p; redk[t] = ks;
  __syncthreads();
  if (t < 128) redk[t] += redk[t + 128];
  __syncthreads();
  if (t < 64) redk[t] += redk[t + 64];
  __syncthreads();
  if (t < 64) {
    float kst = redk[t];
#pragma unroll
    for (int off = 32; off > 0; off >>= 1) kst += __shfl_xor(kst, off);
    const float psum = red[t] + red[64+t] + red[128+t] + red[192+t];
    kv[(size_t)b*1024 + h*64 + t] = psum + kst * bv[h*64 + t];
  }
}

// ---------------------------------------------------------------------------
// K5: per (b,h): state = cumsum_h kv (HEAD-axis cumsum), then
// W2[b,h,d] = sum_dv state[dv] * wo[(h*64+dv), d]
// ---------------------------------------------------------------------------
__global__ __launch_bounds__(256) void k_w2(
    const float* __restrict__ kv, const float* __restrict__ wo,
    float* __restrict__ W2)
{
  const int bh = blockIdx.x;
  const int b = bh >> 4, h = bh & 15;
  const int t = threadIdx.x;
  __shared__ float st[64];
  if (t < 64) {
    float s = 0.f;
    for (int hp = 0; hp <= h; ++hp) s += kv[(size_t)b*1024 + hp*64 + t];
    st[t] = s;
  }
  __syncthreads();
  const int d0 = t * 4;
  float4 acc = {0.f, 0.f, 0.f, 0.f};
#pragma unroll 4
  for (int dv = 0; dv < 64; ++dv) {
    const float sv = st[dv];
    const float4 w4 = *(const float4*)(wo + (size_t)(h*64 + dv)*DD + d0);
    acc.x = fmaf(sv, w4.x, acc.x);
    acc.y = fmaf(sv, w4.y, acc.y);
    acc.z = fmaf(sv, w4.z, acc.z);
    acc.w = fmaf(sv, w4.w, acc.w);
  }
  *(float4*)(W2 + (size_t)(b*HH + h)*DD + d0) = acc;
}

// ---------------------------------------------------------------------------
// K6: out[b,s,:] = bo + sum_h qh[b,s,h] * W2[b,h,:]
// 2048 blocks x 8 rows; s = r*512 + bx -> 512 consecutive rows concurrent.
// Nontemporal stores.
// ---------------------------------------------------------------------------
__global__ __launch_bounds__(256, 4) void k_out(
    const float* __restrict__ qh, const float* __restrict__ W2,
    const float* __restrict__ bo, float* __restrict__ out)
{
  const int bx = blockIdx.x;   // 0..511
  const int b = blockIdx.y;
  const int t = threadIdx.x;
  const int d0 = t * 4;
  float4 w2[16];
#pragma unroll
  for (int h = 0; h < 16; ++h)
    w2[h] = *(const float4*)(W2 + (size_t)(b*HH + h)*DD + d0);
  const float4 bo4 = *(const float4*)(bo + d0);
  __shared__ float qs[128];
  if (t < 128)
    qs[t] = qh[(size_t)(b*SS + (t>>4)*512 + bx)*HH + (t & 15)];
  __syncthreads();
#pragma unroll
  for (int r = 0; r < 8; ++r) {
    const float4* qr = (const float4*)(qs + r*16);
    const float4 q0 = qr[0], q1 = qr[1], q2 = qr[2], q3 = qr[3];
    const float qv[16] = {q0.x,q0.y,q0.z,q0.w, q1.x,q1.y,q1.z,q1.w,
                          q2.x,q2.y,q2.z,q2.w, q3.x,q3.y,q3.z,q3.w};
    float4 o = bo4;
#pragma unroll
    for (int h = 0; h < 16; ++h) {
      o.x = fmaf(qv[h], w2[h].x, o.x);
      o.y = fmaf(qv[h], w2[h].y, o.y);
      o.z = fmaf(qv[h], w2[h].z, o.z);
      o.w = fmaf(qv[h], w2[h].w, o.w);
    }
    nfloat4 ov = { o.x, o.y, o.z, o.w };
    nfloat4* dst = (nfloat4*)(out + (size_t)(b*SS + r*512 + bx)*DD + d0);
    __builtin_nontemporal_store(ov, dst);
  }
}

// ---------------------------------------------------------------------------
extern "C" void kernel_launch(void* const* d_in, const int* in_sizes, int n_in,
                              void* d_out, int out_size, void* d_ws, size_t ws_size,
                              hipStream_t stream)
{
  const float* q  = (const float*)d_in[0];
  const float* k  = (const float*)d_in[1];
  const float* v  = (const float*)d_in[2];
  const float* wq = (const float*)d_in[3];
  const float* bq = (const float*)d_in[4];
  const float* wk = (const float*)d_in[5];
  const float* bk = (const float*)d_in[6];
  const float* wv = (const float*)d_in[7];
  const float* bv = (const float*)d_in[8];
  const float* wo = (const float*)d_in[9];
  const float* bo = (const float*)d_in[10];
  float* out = (float*)d_out;
  float* ws  = (float*)d_ws;

  // ws layout (floats): qh 262144 | kh 262144 | kvt 65536 | kv 4096 | W2 65536
  float* qh  = ws;
  float* kh  = ws + 262144;
  float* kvt = ws + 524288;
  float* kv  = ws + 589824;
  float* W2  = ws + 593920;
  // d_out scratch: kvT partials (1024 blocks * 2048 floats = 8 MB) at the
  // front; wf (weight fragments, 64KB) at +16MB. Both consumed before k_out
  // fully overwrites d_out.
  float* part = out;
  short* wf   = (short*)(out + 4194304);

  hipLaunchKernelGGL(k_wfrag, dim3(2), dim3(256), 0, stream,
                     wq, wk, wf);
  hipLaunchKernelGGL(k_qhkh, dim3(1024), dim3(256), 0, stream,
                     q, k, wf, bq, bk, qh, kh);
  hipLaunchKernelGGL(k_kvt, dim3(32, 8, 4), dim3(256), 0, stream,
                     v, kh, part);
  hipLaunchKernelGGL(k_red, dim3(8, 4, 4), dim3(256), 0, stream,
                     part, kvt);
  hipLaunchKernelGGL(k_kv, dim3(16, 4), dim3(256), 0, stream,
                     kvt, kh, wv, bv, kv);
  hipLaunchKernelGGL(k_w2, dim3(64), dim3(256), 0, stream,
                     kv, wo, W2);
  hipLaunchKernelGGL(k_out, dim3(512, 4), dim3(256), 0, stream,
                     qh, W2, bo, out);
}